// Round 17
// baseline (392.390 us; speedup 1.0000x reference)
//
#include <hip/hip_runtime.h>
#include <math.h>

// ---------------- problem constants ----------------
#define LAYERS 2
#define DMODEL 256
#define NHEAD  8
#define DHEAD  32
#define FF     512
#define KNB    9
#define MB     4
#define G1D    40
#define G2D    40
#define NTGT   2048
#define NCTX   1600          // G1D*G2D
#define RC     (MB*NCTX)     // 6400 grid rows
#define RT     (MB*NTGT)     // 8192 target rows
#define NSPLIT 4             // sa_attn key-split factor

typedef __attribute__((ext_vector_type(8))) short short8;   // 8 bf16 (4 VGPRs)
typedef __attribute__((ext_vector_type(4))) float f32x4;    // mfma C/D

#if __has_builtin(__builtin_amdgcn_exp2f)
#define EXP2(x) __builtin_amdgcn_exp2f(x)
#else
#define EXP2(x) exp2f(x)
#endif
#define L2E 1.4426950408889634f
#define ATTN_SCALE 0.17677669529663687f   // 1/sqrt(32)

// ---------------- workspace layout (float offsets) ----------------
#define ZC_OFF    0
#define HC_OFF    1638400                      // bf16 normalize(zc): 819200 f
#define HT_OFF    (HC_OFF + 819200)            // bf16 normalize(zt)
#define QKV_OFF   (HC_OFF + 2097152)
#define WT_OFF    (QKV_OFF + 3400000)          // bf16 wT (tail of QKV region)
#define FB_OFF    (QKV_OFF + 4500000)          // folded biases
#define Q_OFF     (QKV_OFF + 4915200)          // CA q fp32
#define O_OFF     (Q_OFF + 2097152)            // CA out bf16
#define IDX_OFF   (O_OFF + 2097152)
#define MASK_OFF  (IDX_OFF + 73728)
#define OPART_OFF (MASK_OFF + 73728)           // SA O-partials: NSPLIT*RC*256 bf16
#define LB_OFF    (OPART_OFF + 3276800)        // SA l-partials: NSPLIT*RC*8 f
#define WS_FLOATS (LB_OFF + 204800)

// per-layer wT offsets (shorts)
#define WT_LAYER   1048576
#define WT_QKV     0
#define WT_WO      196608
#define WT_W1      262144
#define WT_W2      393216
#define WT_CWQ     524288
#define WT_CWKV    589824
#define WT_CWO     720896
#define WT_CW1     786432
#define WT_CW2     917504
// per-layer folded-bias offsets (floats), layer stride 2560
#define FB_LAYER   2560
#define FB_QKV     0
#define FB_W1      768
#define FB_WKV     1280
#define FB_WQ      1792
#define FB_CW1     2048

static __device__ __forceinline__ float gelu_f(float x){
  float t = tanhf(0.7978845608028654f * (x + 0.044715f * x * x * x));
  return 0.5f * x * (1.0f + t);
}
static __device__ __forceinline__ unsigned int bf16_rne(float x){
  unsigned int u = __float_as_uint(x);
  return (u + 0x7fffu + ((u >> 16) & 1u)) >> 16;
}
static __device__ __forceinline__ unsigned int pack_bf16x2(float lo, float hi){
  return bf16_rne(lo) | (bf16_rne(hi) << 16);
}
static __device__ __forceinline__ float bfu(unsigned int u16){
  return __uint_as_float(u16 << 16);
}

// ------ weight prep: fp32 [K][N] -> bf16 [N][K], row-scaled by gamma, col-scaled -----
struct TDesc { const float* src; const float* gamma; int dstoff; int K; int N; int nse; float nsc; };
struct TTable { TDesc e[18]; };

__global__ __launch_bounds__(256)
void wprep_kernel(TTable t, unsigned short* __restrict__ wt){
  TDesc d = t.e[blockIdx.z];
  int n0 = blockIdx.x * 32, k0 = blockIdx.y * 32;
  if (n0 >= d.N || k0 >= d.K) return;
  __shared__ float tile[32][33];
  int tx = threadIdx.x, ty = threadIdx.y;
  float csc = (n0 + tx < d.nse) ? d.nsc : 1.0f;
  #pragma unroll
  for (int j = 0; j < 4; j++){
    int k = k0 + ty * 4 + j;
    float v = d.src[(size_t)k * d.N + n0 + tx];
    if (d.gamma) v *= d.gamma[k];
    tile[ty * 4 + j][tx] = v * csc;
  }
  __syncthreads();
  #pragma unroll
  for (int j = 0; j < 4; j++)
    wt[(size_t)d.dstoff + (size_t)(n0 + ty * 4 + j) * d.K + k0 + tx] =
        (unsigned short)bf16_rne(tile[tx][ty * 4 + j]);
}

// ---------------- bias fold (parallel): fb[n] = (base[n] + sum_k beta[k]*W[k][n])*sc -
struct BDesc { const float* W; const float* beta; const float* base; int outoff; int N; int nse; float nsc; };
struct BTable { BDesc e[10]; };

__global__ __launch_bounds__(256)
void bfold_kernel(BTable t, float* __restrict__ fb){
  BDesc d = t.e[blockIdx.x];
  int n = blockIdx.y * 64 + (threadIdx.x >> 2);
  int q = threadIdx.x & 3;
  if (n >= d.N) return;
  float s = 0.f;
  #pragma unroll 4
  for (int k = q * 64; k < q * 64 + 64; k++)
    s += d.beta[k] * d.W[(size_t)k * d.N + n];
  s += __shfl_xor(s, 1);
  s += __shfl_xor(s, 2);
  if (q == 0){
    float r = s + (d.base ? d.base[n] : 0.f);
    if (n < d.nse) r *= d.nsc;
    fb[d.outoff + n] = r;
  }
}

// ---------------- nearest-grid-neighbour index/mask precompute ----------------
__global__ void nn_idx_kernel(const float* __restrict__ xc, const float* __restrict__ xt,
                              int* __restrict__ idx, float* __restrict__ mask){
  int g = blockIdx.x * blockDim.x + threadIdx.x;
  if (g >= MB * NTGT) return;
  int m = g >> 11;
  float x0 = xt[(size_t)g * 2 + 0];
  float x1 = xt[(size_t)g * 2 + 1];
  const float* xcm = xc + (size_t)m * G1D * G2D * 2;
  int n0 = 0; float b0 = 1e30f;
  for (int i = 0; i < G1D; i++){
    float d = fabsf(x0 - xcm[i * (G2D * 2)]);
    if (d < b0){ b0 = d; n0 = i; }
  }
  int n1 = 0; float b1 = 1e30f;
  for (int j = 0; j < G2D; j++){
    float d = fabsf(x1 - xcm[j * 2 + 1]);
    if (d < b1){ b1 = d; n1 = j; }
  }
  #pragma unroll
  for (int a = 0; a < 3; a++){
    int r0 = n0 + a - 1;
    bool v0 = (r0 >= 0) && (r0 < G1D);
    int i0 = min(max(r0, 0), G1D - 1);
    #pragma unroll
    for (int b = 0; b < 3; b++){
      int r1 = n1 + b - 1;
      bool v1 = (r1 >= 0) && (r1 < G2D);
      int i1 = min(max(r1, 0), G2D - 1);
      idx [(size_t)g * KNB + a * 3 + b] = i0 * G2D + i1;
      mask[(size_t)g * KNB + a * 3 + b] = (v0 && v1) ? 1.0f : 0.0f;
    }
  }
}

// ---------------- LayerNorm normalize-only, bf16 out (single + dual-tensor) ----------
static __device__ __forceinline__ void ln_row(const float* __restrict__ xr,
                                              unsigned short* __restrict__ yr, int lane){
  int d0 = lane * 4;
  float4 xv = *(const float4*)(xr + d0);
  float s = xv.x + xv.y + xv.z + xv.w;
  #pragma unroll
  for (int off = 32; off > 0; off >>= 1) s += __shfl_xor(s, off);
  float mu = s * (1.0f / DMODEL);
  float dx0 = xv.x - mu, dx1 = xv.y - mu, dx2 = xv.z - mu, dx3 = xv.w - mu;
  float v = dx0*dx0 + dx1*dx1 + dx2*dx2 + dx3*dx3;
  #pragma unroll
  for (int off = 32; off > 0; off >>= 1) v += __shfl_xor(v, off);
  float rs = rsqrtf(v * (1.0f / DMODEL) + 1e-5f);
  uint2 w;
  w.x = pack_bf16x2(dx0 * rs, dx1 * rs);
  w.y = pack_bf16x2(dx2 * rs, dx3 * rs);
  *(uint2*)(yr + d0) = w;
}

__global__ __launch_bounds__(256)
void ln_norm(const float* __restrict__ x, unsigned short* __restrict__ y, int rows){
  int gw   = blockIdx.x * 4 + (threadIdx.x >> 6);
  int lane = threadIdx.x & 63;
  if (gw >= rows) return;
  ln_row(x + (size_t)gw * DMODEL, y + (size_t)gw * DMODEL, lane);
}

// dual: rows [0,ra) from xa->ya; rows [ra, ra+rb) from xb->yb
__global__ __launch_bounds__(256)
void ln_norm2(const float* __restrict__ xa, unsigned short* __restrict__ ya, int ra,
              const float* __restrict__ xb, unsigned short* __restrict__ yb){
  int gw   = blockIdx.x * 4 + (threadIdx.x >> 6);
  int lane = threadIdx.x & 63;
  if (gw < ra)
    ln_row(xa + (size_t)gw * DMODEL, ya + (size_t)gw * DMODEL, lane);
  else {
    int g2 = gw - ra;
    ln_row(xb + (size_t)g2 * DMODEL, yb + (size_t)g2 * DMODEL, lane);
  }
}

// ================= MFMA GEMM, templated tile (MTxNT), BK=64 dbuf, glds staging ======
template<int ROWS>
static __device__ __forceinline__ void stage_glds(const unsigned short* __restrict__ src,
                                                  int Ksrc, unsigned short* lds,
                                                  int wave, int lane){
  #pragma unroll
  for (int j = 0; j < ROWS / 32; j++){
    int ublk = (j * 4 + wave) * 64;          // wave-uniform first 16B-unit
    int u    = ublk + lane;
    int row  = u >> 3;                       // 8 units (128B) per row
    int unit = (u & 7) ^ (row & 7);          // source pre-swizzle
    __builtin_amdgcn_global_load_lds(
        (const __attribute__((address_space(1))) void*)(src + (size_t)row * Ksrc + unit * 8),
        (__attribute__((address_space(3))) void*)(lds + (size_t)ublk * 8),
        16, 0, 0);
  }
}

template<int K, int MT, int NT>
__global__ __launch_bounds__(256)
void gemm_glds(const unsigned short* __restrict__ A, const unsigned short* __restrict__ Wt,
               const float* __restrict__ bias, const float* __restrict__ res,
               void* __restrict__ C, int N, int flags){
  const int MFR = MT / 32, NFR = NT / 32;    // 16x16 frags per wave
  __shared__ unsigned short Als[2][MT * 64];
  __shared__ unsigned short Bls[2][NT * 64];
  int tid = threadIdx.x;
  int wave = tid >> 6, lane = tid & 63;
  int wm = wave >> 1, wn = wave & 1;
  int l16 = lane & 15, grp = lane >> 4;
  int r0 = blockIdx.y * MT, c0 = blockIdx.x * NT;

  const unsigned short* Ag = A  + (size_t)r0 * K;
  const unsigned short* Bg = Wt + (size_t)c0 * K;
  const int nch = K >> 6;

  stage_glds<MT>(Ag, K, Als[0], wave, lane);
  stage_glds<NT>(Bg, K, Bls[0], wave, lane);

  f32x4 acc[MFR][NFR];
  #pragma unroll
  for (int m = 0; m < MFR; m++)
    #pragma unroll
    for (int n = 0; n < NFR; n++) acc[m][n] = (f32x4){0.f, 0.f, 0.f, 0.f};

  #pragma unroll
  for (int ch = 0; ch < nch; ch++){
    int b = ch & 1;
    __syncthreads();
    if (ch + 1 < nch){
      stage_glds<MT>(Ag + (ch + 1) * 64, K, Als[b ^ 1], wave, lane);
      stage_glds<NT>(Bg + (ch + 1) * 64, K, Bls[b ^ 1], wave, lane);
    }
    const unsigned short* Ab = Als[b];
    const unsigned short* Bb = Bls[b];
    #pragma unroll
    for (int kk = 0; kk < 2; kk++){
      short8 af[MFR], bfr[NFR];
      #pragma unroll
      for (int m = 0; m < MFR; m++){
        int row = wm * (MT / 2) + m * 16 + l16;
        int unit = (kk * 4 + grp) ^ (row & 7);
        af[m] = *(const short8*)(Ab + row * 64 + unit * 8);
      }
      #pragma unroll
      for (int n = 0; n < NFR; n++){
        int row = wn * (NT / 2) + n * 16 + l16;
        int unit = (kk * 4 + grp) ^ (row & 7);
        bfr[n] = *(const short8*)(Bb + row * 64 + unit * 8);
      }
      #pragma unroll
      for (int m = 0; m < MFR; m++)
        #pragma unroll
        for (int n = 0; n < NFR; n++)
          acc[m][n] = __builtin_amdgcn_mfma_f32_16x16x32_bf16(af[m], bfr[n], acc[m][n], 0, 0, 0);
    }
  }

  #pragma unroll
  for (int n = 0; n < NFR; n++){
    int gc = c0 + wn * (NT / 2) + n * 16 + l16;
    float bv = (flags & 1) ? bias[gc] : 0.f;
    #pragma unroll
    for (int m = 0; m < MFR; m++){
      int grb = r0 + wm * (MT / 2) + m * 16 + grp * 4;
      #pragma unroll
      for (int r = 0; r < 4; r++){
        float v = acc[m][n][r] + bv;
        if (flags & 2) v = gelu_f(v);
        if (flags & 4) v += res[(size_t)(grb + r) * N + gc];
        if (flags & 8) ((unsigned short*)C)[(size_t)(grb + r) * N + gc] = (unsigned short)bf16_rne(v);
        else           ((float*)C)[(size_t)(grb + r) * N + gc] = v;
      }
    }
  }
}

// ------- WO GEMM with fused 4-way key-split merge on the A operand ------------------
// A[row][col] = sum_s w_s(row, head(col)) * opart[s][row][col], w_s = l_s / sum l.
// A staged once for full K=256 (32KB LDS), unit-XOR-swizzled to match core reads.
// B double-buffered via global_load_lds. C = A@Wt + res (fp32). N=K=256, tile 64x64.
__global__ __launch_bounds__(256)
void gemm_womerge(const unsigned short* __restrict__ opart, const float* __restrict__ lb,
                  const unsigned short* __restrict__ Wt, const float* __restrict__ res,
                  float* __restrict__ C){
  __shared__ unsigned short Als[64 * 256];
  __shared__ unsigned short Bls[2][64 * 64];
  int tid = threadIdx.x;
  int wave = tid >> 6, lane = tid & 63;
  int wm = wave >> 1, wn = wave & 1;
  int l16 = lane & 15, grp = lane >> 4;
  int r0 = blockIdx.y * 64, c0 = blockIdx.x * 64;

  const unsigned short* Bg = Wt + (size_t)c0 * 256;
  stage_glds<64>(Bg, 256, Bls[0], wave, lane);

  // build merged A: 4 threads/row, each 64 cols (= 2 heads, 8 units)
  {
    int row = tid >> 2;
    int cseg = (tid & 3) * 64;
    int gr = r0 + row;
    int h0 = cseg >> 5;
    float w0[NSPLIT], w1[NSPLIT];
    float ls0 = 0.f, ls1 = 0.f;
    #pragma unroll
    for (int s = 0; s < NSPLIT; s++){
      w0[s] = lb[(size_t)(s * RC + gr) * 8 + h0];
      w1[s] = lb[(size_t)(s * RC + gr) * 8 + h0 + 1];
      ls0 += w0[s]; ls1 += w1[s];
    }
    float i0 = 1.0f / ls0, i1 = 1.0f / ls1;
    #pragma unroll
    for (int s = 0; s < NSPLIT; s++){ w0[s] *= i0; w1[s] *= i1; }

    #pragma unroll
    for (int u = 0; u < 8; u++){
      int gcol = cseg + u * 8;
      const float* w = (u < 4) ? w0 : w1;     // first 4 units = head h0, rest = h0+1
      float o[8] = {0,0,0,0,0,0,0,0};
      #pragma unroll
      for (int s = 0; s < NSPLIT; s++){
        short8 a = *(const short8*)(opart + (size_t)(s * RC + gr) * DMODEL + gcol);
        float ws = w[s];
        #pragma unroll
        for (int j = 0; j < 8; j++)
          o[j] += bfu((unsigned short)a[j]) * ws;
      }
      short8 sv;
      #pragma unroll
      for (int j = 0; j < 8; j++) sv[j] = (short)bf16_rne(o[j]);
      int gu = gcol >> 3;
      int slot = (gu & ~7) | ((gu & 7) ^ (row & 7));
      *(short8*)&Als[row * 256 + slot * 8] = sv;
    }
  }

  f32x4 acc[2][2];
  #pragma unroll
  for (int m = 0; m < 2; m++)
    #pragma unroll
    for (int n = 0; n < 2; n++) acc[m][n] = (f32x4){0.f, 0.f, 0.f, 0.f};

  #pragma unroll
  for (int ch = 0; ch < 4; ch++){
    int b = ch & 1;
    __syncthreads();
    if (ch + 1 < 4)
      stage_glds<64>(Bg + (ch + 1) * 64, 256, Bls[b ^ 1], wave, lane);
    const unsigned short* Bb = Bls[b];
    #pragma unroll
    for (int kk = 0; kk < 2; kk++){
      short8 af[2], bfr[2];
      #pragma unroll
      for (int m = 0; m < 2; m++){
        int row = wm * 32 + m * 16 + l16;
        int slot = ch * 8 + ((kk * 4 + grp) ^ (row & 7));
        af[m] = *(const short8*)(Als + row * 256 + slot * 8);
      }
      #pragma unroll
      for (int n = 0; n < 2; n++){
        int row = wn * 32 + n * 16 + l16;
        int unit = (kk * 4 + grp) ^ (row & 7);
        bfr[n] = *(const short8*)(Bb + row * 64 + unit * 8);
      }
      #pragma unroll
      for (int m = 0; m < 2; m++)
        #pragma unroll
        for (int n = 0; n < 2; n++)
          acc[m][n] = __builtin_amdgcn_mfma_f32_16x16x32_bf16(af[m], bfr[n], acc[m][n], 0, 0, 0);
    }
  }

  #pragma unroll
  for (int n = 0; n < 2; n++){
    int gc = c0 + wn * 32 + n * 16 + l16;
    #pragma unroll
    for (int m = 0; m < 2; m++){
      int grb = r0 + wm * 32 + m * 16 + grp * 4;
      #pragma unroll
      for (int r = 0; r < 4; r++){
        float v = acc[m][n][r] + res[(size_t)(grb + r) * 256 + gc];
        C[(size_t)(grb + r) * 256 + gc] = v;
      }
    }
  }
}

// ------- batched wkv (z=0) + wq (z=1) GEMM: both K=256, tile 64x64, bias, fp32 out --
__global__ __launch_bounds__(256)
void gemm_wkvq(const unsigned short* __restrict__ A0, const unsigned short* __restrict__ W0,
               const float* __restrict__ b0, float* __restrict__ C0,
               const unsigned short* __restrict__ A1, const unsigned short* __restrict__ W1,
               const float* __restrict__ b1, float* __restrict__ C1){
  int z = blockIdx.z;
  int N = z ? 256 : 512;
  int R = z ? RT : RC;
  if ((int)blockIdx.x * 64 >= N || (int)blockIdx.y * 64 >= R) return;
  const unsigned short* A  = z ? A1 : A0;
  const unsigned short* Wt = z ? W1 : W0;
  const float* bias        = z ? b1 : b0;
  float* C                 = z ? C1 : C0;

  __shared__ unsigned short Als[2][64 * 64];
  __shared__ unsigned short Bls[2][64 * 64];
  int tid = threadIdx.x;
  int wave = tid >> 6, lane = tid & 63;
  int wm = wave >> 1, wn = wave & 1;
  int l16 = lane & 15, grp = lane >> 4;
  int r0 = blockIdx.y * 64, c0 = blockIdx.x * 64;

  const unsigned short* Ag = A  + (size_t)r0 * 256;
  const unsigned short* Bg = Wt + (size_t)c0 * 256;

  stage_glds<64>(Ag, 256, Als[0], wave, lane);
  stage_glds<64>(Bg, 256, Bls[0], wave, lane);

  f32x4 acc[2][2];
  #pragma unroll
  for (int m = 0; m < 2; m++)
    #pragma unroll
    for (int n = 0; n < 2; n++) acc[m][n] = (f32x4){0.f, 0.f, 0.f, 0.f};

  #pragma unroll
  for (int ch = 0; ch < 4; ch++){
    int b = ch & 1;
    __syncthreads();
    if (ch + 1 < 4){
      stage_glds<64>(Ag + (ch + 1) * 64, 256, Als[b ^ 1], wave, lane);
      stage_glds<64>(Bg + (ch + 1) * 64, 256, Bls[b ^ 1], wave, lane);
    }
    const unsigned short* Ab = Als[b];
    const unsigned short* Bb = Bls[b];
    #pragma unroll
    for (int kk = 0; kk < 2; kk++){
      short8 af[2], bfr[2];
      #pragma unroll
      for (int m = 0; m < 2; m++){
        int row = wm * 32 + m * 16 + l16;
        int unit = (kk * 4 + grp) ^ (row & 7);
        af[m] = *(const short8*)(Ab + row * 64 + unit * 8);
      }
      #pragma unroll
      for (int n = 0; n < 2; n++){
        int row = wn * 32 + n * 16 + l16;
        int unit = (kk * 4 + grp) ^ (row & 7);
        bfr[n] = *(const short8*)(Bb + row * 64 + unit * 8);
      }
      #pragma unroll
      for (int m = 0; m < 2; m++)
        #pragma unroll
        for (int n = 0; n < 2; n++)
          acc[m][n] = __builtin_amdgcn_mfma_f32_16x16x32_bf16(af[m], bfr[n], acc[m][n], 0, 0, 0);
    }
  }

  #pragma unroll
  for (int n = 0; n < 2; n++){
    int gc = c0 + wn * 32 + n * 16 + l16;
    float bv = bias[gc];
    #pragma unroll
    for (int m = 0; m < 2; m++){
      int grb = r0 + wm * 32 + m * 16 + grp * 4;
      #pragma unroll
      for (int r = 0; r < 4; r++)
        C[(size_t)(grb + r) * N + gc] = acc[m][n][r] + bv;
    }
  }
}

// ------- self-attention: bf16 MFMA flash, KEY-SPLIT x4, FIXED-SHIFT softmax ---------
#define KSTR 40
#define VSTR 70
#define PSTR 72
__global__ __launch_bounds__(256)
void sa_attn_mfma(const unsigned short* __restrict__ qkv,
                  unsigned short* __restrict__ opart, float* __restrict__ lb){
  int mz = blockIdx.z;
  int m = mz & 3, split = mz >> 2;           // split 0..3
  int h = blockIdx.y;
  int tid  = threadIdx.x;
  int wave = tid >> 6, lane = tid & 63;
  int qr = lane & 15, grp = lane >> 4;
  int q0 = blockIdx.x * 64 + wave * 16;

  int kt0 = split ? (7 + (split - 1) * 6) : 0;
  int kt1 = kt0 + (split ? 6 : 7);

  __shared__ unsigned short Kls[2][64 * KSTR];
  __shared__ unsigned short Vls[2][32 * VSTR];
  __shared__ unsigned short Pls[4][16 * PSTR];
  unsigned short* Pw = Pls[wave];

  short8 qf = *(const short8*)(qkv + ((size_t)(m * NCTX + q0 + qr)) * 768 + h * 32 + grp * 8);

  int skey = tid >> 2;
  int scol = (tid & 3) * 8;
  const unsigned short* kbase = qkv + (size_t)m * NCTX * 768 + 256 + h * 32 + scol;

  uint4 kreg = *(const uint4*)(kbase + (size_t)(kt0 * 64 + skey) * 768);
  uint4 vreg = *(const uint4*)(kbase + (size_t)(kt0 * 64 + skey) * 768 + 256);

  float lq = 0.0f;                       // per-thread partial sum of P
  f32x4 acc0 = {0.f, 0.f, 0.f, 0.f};
  f32x4 acc1 = {0.f, 0.f, 0.f, 0.f};

  {
    *(uint4*)&Kls[0][skey * KSTR + scol] = kreg;
    unsigned int vv[4] = {vreg.x, vreg.y, vreg.z, vreg.w};
    #pragma unroll
    for (int j = 0; j < 4; j++){
      Vls[0][(scol + 2 * j    ) * VSTR + skey] = (unsigned short)(vv[j] & 0xffffu);
      Vls[0][(scol + 2 * j + 1) * VSTR + skey] = (unsigned short)(vv[j] >> 16);
    }
  }

  for (int kt = kt0; kt < kt1; kt++){
    int b = (kt - kt0) & 1;
    __syncthreads();
    if (kt + 1 < kt1){
      kreg = *(const uint4*)(kbase + (size_t)((kt + 1) * 64 + skey) * 768);
      vreg = *(const uint4*)(kbase + (size_t)((kt + 1) * 64 + skey) * 768 + 256);
    }

    f32x4 s0 = {0.f,0.f,0.f,0.f}, s1 = {0.f,0.f,0.f,0.f};
    f32x4 s2 = {0.f,0.f,0.f,0.f}, s3 = {0.f,0.f,0.f,0.f};
    {
      const short8 k0 = *(const short8*)&Kls[b][( 0 + qr) * KSTR + grp * 8];
      const short8 k1 = *(const short8*)&Kls[b][(16 + qr) * KSTR + grp * 8];
      const short8 k2 = *(const short8*)&Kls[b][(32 + qr) * KSTR + grp * 8];
      const short8 k3 = *(const short8*)&Kls[b][(48 + qr) * KSTR + grp * 8];
      s0 = __builtin_amdgcn_mfma_f32_16x16x32_bf16(k0, qf, s0, 0, 0, 0);
      s1 = __builtin_amdgcn_mfma_f32_16x16x32_bf16(k1, qf, s1, 0, 0, 0);
      s2 = __builtin_amdgcn_mfma_f32_16x16x32_bf16(k2, qf, s2, 0, 0, 0);
      s3 = __builtin_amdgcn_mfma_f32_16x16x32_bf16(k3, qf, s3, 0, 0, 0);
    }

    float p[4][4];
    #pragma unroll
    for (int r = 0; r < 4; r++){
      p[0][r] = EXP2(s0[r]); p[1][r] = EXP2(s1[r]);
      p[2][r] = EXP2(s2[r]); p[3][r] = EXP2(s3[r]);
    }
    #pragma unroll
    for (int kb = 0; kb < 4; kb++)
      #pragma unroll
      for (int r = 0; r < 4; r++) lq += p[kb][r];

    #pragma unroll
    for (int kb = 0; kb < 4; kb++){
      *(unsigned int*)&Pw[qr * PSTR + kb * 16 + grp * 4]     = pack_bf16x2(p[kb][0], p[kb][1]);
      *(unsigned int*)&Pw[qr * PSTR + kb * 16 + grp * 4 + 2] = pack_bf16x2(p[kb][2], p[kb][3]);
    }

    #pragma unroll
    for (int hh = 0; hh < 2; hh++){
      const short8 pf = *(const short8*)&Pw[qr * PSTR + hh * 32 + grp * 8];
      const short8 v0 = *(const short8*)&Vls[b][( 0 + qr) * VSTR + hh * 32 + grp * 8];
      const short8 v1 = *(const short8*)&Vls[b][(16 + qr) * VSTR + hh * 32 + grp * 8];
      acc0 = __builtin_amdgcn_mfma_f32_16x16x32_bf16(v0, pf, acc0, 0, 0, 0);
      acc1 = __builtin_amdgcn_mfma_f32_16x16x32_bf16(v1, pf, acc1, 0, 0, 0);
    }

    if (kt + 1 < kt1){
      *(uint4*)&Kls[b ^ 1][skey * KSTR + scol] = kreg;
      unsigned int vv[4] = {vreg.x, vreg.y, vreg.z, vreg.w};
      #pragma unroll
      for (int j = 0; j < 4; j++){
        Vls[b ^ 1][(scol + 2 * j    ) * VSTR + skey] = (unsigned short)(vv[j] & 0xffffu);
        Vls[b ^ 1][(scol + 2 * j + 1) * VSTR + skey] = (unsigned short)(vv[j] >> 16);
      }
    }
  }

  lq += __shfl_xor(lq, 16);
  lq += __shfl_xor(lq, 32);
  float inv = 1.0f / lq;
  int gr = m * NCTX + q0 + qr;
  unsigned short* op = opart + ((size_t)(split * RC + gr)) * DMODEL + h * DHEAD;
  uint2 o16a, o16b;
  o16a.x = pack_bf16x2(acc0[0] * inv, acc0[1] * inv);
  o16a.y = pack_bf16x2(acc0[2] * inv, acc0[3] * inv);
  o16b.x = pack_bf16x2(acc1[0] * inv, acc1[1] * inv);
  o16b.y = pack_bf16x2(acc1[2] * inv, acc1[3] * inv);
  *(uint2*)(op + grp * 4)      = o16a;
  *(uint2*)(op + 16 + grp * 4) = o16b;
  if (grp == 0)
    lb[((size_t)(split * RC + gr)) * 8 + h] = lq;
}

// ------- cross-attention over 9 gathered neighbours (q pre-scaled at wprep) ---------
__global__ __launch_bounds__(256)
void ca_attn_kernel(const float* __restrict__ qb, const float* __restrict__ kv,
                    const int* __restrict__ idx, const float* __restrict__ mask,
                    unsigned short* __restrict__ ob){
  int g = blockIdx.x;
  int m = g >> 11;
  int tid = threadIdx.x;
  float q = qb[(size_t)g * DMODEL + tid];
  float s[KNB];
  int rws[KNB];
  #pragma unroll
  for (int k = 0; k < KNB; k++){
    int row = idx[(size_t)g * KNB + k];
    rws[k] = row;
    float p = q * kv[((size_t)(m * NCTX + row)) * 512 + tid];
    #pragma unroll
    for (int off = 16; off > 0; off >>= 1) p += __shfl_xor(p, off, 32);
    s[k] = (mask[(size_t)g * KNB + k] > 0.5f) ? p : -1e30f;
  }
  float sm = s[0];
  #pragma unroll
  for (int k = 1; k < KNB; k++) sm = fmaxf(sm, s[k]);
  float den = 0.f, w[KNB];
  #pragma unroll
  for (int k = 0; k < KNB; k++){ w[k] = __expf(s[k] - sm); den += w[k]; }
  float inv = 1.0f / den;
  float o = 0.f;
  #pragma unroll
  for (int k = 0; k < KNB; k++)
    o += w[k] * kv[((size_t)(m * NCTX + rws[k])) * 512 + 256 + tid];
  ob[(size_t)g * DMODEL + tid] = (unsigned short)bf16_rne(o * inv);
}

// ---------------- host launch helper ----------------
static inline void launch_gemm(const unsigned short* A, const unsigned short* Wt,
                               const float* bias, const float* res, void* C,
                               int R, int K, int N, int flags, hipStream_t stream){
  if (N == 768){
    gemm_glds<256, 64, 128><<<dim3(N / 128, R / 64), 256, 0, stream>>>(A, Wt, bias, res, C, N, flags);
  } else if (K == 256){
    gemm_glds<256, 64, 64><<<dim3(N / 64, R / 64), 256, 0, stream>>>(A, Wt, bias, res, C, N, flags);
  } else {
    gemm_glds<512, 64, 64><<<dim3(N / 64, R / 64), 256, 0, stream>>>(A, Wt, bias, res, C, N, flags);
  }
}

// ---------------- host launcher ----------------
extern "C" void kernel_launch(void* const* d_in, const int* in_sizes, int n_in,
                              void* d_out, int out_size, void* d_ws, size_t ws_size,
                              hipStream_t stream){
  const float* xc      = (const float*)d_in[0];
  const float* zc_in   = (const float*)d_in[1];
  const float* xt      = (const float*)d_in[2];
  const float* zt_in   = (const float*)d_in[3];
  const float* sa_wqkv = (const float*)d_in[4];
  const float* sa_wo   = (const float*)d_in[5];
  const float* sa_ln1  = (const float*)d_in[6];
  const float* sa_ln2  = (const float*)d_in[7];
  const float* sa_w1   = (const float*)d_in[8];
  const float* sa_b1   = (const float*)d_in[9];
  const float* sa_w2   = (const float*)d_in[10];
  const float* sa_b2   = (const float*)d_in[11];
  const float* ca_wq   = (const float*)d_in[12];
  const float* ca_wkv  = (const float*)d_in[13];
  const float* ca_wo   = (const float*)d_in[14];
  const float* ca_lnq  = (const float*)d_in[15];
  const float* ca_lnkv = (const float*)d_in[16];
  const float* ca_ln2  = (const float*)d_in[17];
  const float* ca_w1   = (const float*)d_in[18];
  const float* ca_b1   = (const float*)d_in[19];
  const float* ca_w2   = (const float*)d_in[20];
  const float* ca_b2   = (const float*)d_in[21];

  if (ws_size < (size_t)WS_FLOATS * sizeof(float)) return;
  float* ws    = (float*)d_ws;
  float* zc    = ws + ZC_OFF;
  unsigned short* hc16 = (unsigned short*)(ws + HC_OFF);   // normalize(zc) bf16
  unsigned short* ht16 = (unsigned short*)(ws + HT_OFF);   // normalize(zt) bf16
  float* qkvb  = ws + QKV_OFF;   // aliased: bf16 qkv / fp32 CA kv / bf16 ffn-mid
  unsigned short* qkv16 = (unsigned short*)qkvb;
  unsigned short* wt    = (unsigned short*)(ws + WT_OFF);
  float* fb    = ws + FB_OFF;
  float* qb    = ws + Q_OFF;                               // CA q
  unsigned short* ob16    = (unsigned short*)(ws + O_OFF); // CA out
  unsigned short* opart16 = (unsigned short*)(ws + OPART_OFF);
  float* lbuf  = ws + LB_OFF;
  int*   idxb  = (int*)(ws + IDX_OFF);
  float* maskb = ws + MASK_OFF;
  float* zt    = (float*)d_out;

  const float QSC = ATTN_SCALE * L2E;   // folded into sa Q (exp2-domain softmax)

  // ---- weight prep (transpose + gamma row-scale + Q col-scale) ----
  TTable tt;
  for (int l = 0; l < LAYERS; l++){
    int b = l * WT_LAYER, i = l * 9;
    tt.e[i + 0] = { sa_wqkv + (size_t)l * 256 * 768, sa_ln1  + l * 512, b + WT_QKV,  256, 768, 256, QSC };
    tt.e[i + 1] = { sa_wo   + (size_t)l * 256 * 256, nullptr,           b + WT_WO,   256, 256, 0, 1.f };
    tt.e[i + 2] = { sa_w1   + (size_t)l * 256 * 512, sa_ln2  + l * 512, b + WT_W1,   256, 512, 0, 1.f };
    tt.e[i + 3] = { sa_w2   + (size_t)l * 512 * 256, nullptr,           b + WT_W2,   512, 256, 0, 1.f };
    tt.e[i + 4] = { ca_wq   + (size_t)l * 256 * 256, ca_lnq  + l * 512, b + WT_CWQ,  256, 256, 256, ATTN_SCALE };
    tt.e[i + 5] = { ca_wkv  + (size_t)l * 256 * 512, ca_lnkv + l * 512, b + WT_CWKV, 256, 512, 0, 1.f };
    tt.e[i + 6] = { ca_wo   + (size_t)l * 256 * 256, nullptr,           b + WT_CWO,  256, 256, 0, 1.f };
    tt.e[i + 7] = { ca_w1   + (size_t)l * 256 * 512, ca_ln2  + l * 512, b + WT_CW1,  256, 512, 0, 1.f };
    tt.e[i + 8] = { ca_w2   + (size_t)l * 512 * 256, nullptr,           b + WT_CW2,  512, 256, 0, 1.f };
  }
  wprep_kernel<<<dim3(24, 16, 18), dim3(32, 8), 0, stream>>>(tt, wt);

  // ---- beta fold into biases (parallel; Q-part scaled to match) ----
  BTable bt;
  for (int l = 0; l < LAYERS; l++){
    int fo = l * FB_LAYER, i = l * 5;
    bt.e[i + 0] = { sa_wqkv + (size_t)l * 256 * 768, sa_ln1  + l * 512 + 256, nullptr,        fo + FB_QKV, 768, 256, QSC };
    bt.e[i + 1] = { sa_w1   + (size_t)l * 256 * 512, sa_ln2  + l * 512 + 256, sa_b1 + l * FF, fo + FB_W1,  512, 0, 1.f };
    bt.e[i + 2] = { ca_wkv  + (size_t)l * 256 * 512, ca_lnkv + l * 512 + 256, nullptr,        fo + FB_WKV, 512, 0, 1.f };
    bt.e[i + 3] = { ca_wq   + (size_t)l * 256 * 256, ca_lnq  + l * 512 + 256, nullptr,        fo + FB_WQ,  256, 256, ATTN_SCALE };
    bt.e[i + 4] = { ca_w1   + (size_t)l * 256 * 512, ca_ln2  + l * 512 + 256, ca_b1 + l * FF, fo + FB_CW1, 512, 0, 1.f };
  }
  bfold_kernel<<<dim3(10, 12), 256, 0, stream>>>(bt, fb);

  nn_idx_kernel<<<(MB * NTGT) / 256, 256, 0, stream>>>(xc, xt, idxb, maskb);

  // upfront normalize(zc); post-FFN normalize is shared by ca_wkv and next-layer qkv
  ln_norm<<<RC / 4, 256, 0, stream>>>(zc_in, hc16, RC);

  for (int l = 0; l < LAYERS; l++){
    const unsigned short* wl = wt + (size_t)l * WT_LAYER;
    const float* fl = fb + (size_t)l * FB_LAYER;
    const float* zc_src = (l == 0) ? zc_in : zc;
    const float* zt_src = (l == 0) ? zt_in : zt;

    // ---------- self-attention block on zc ----------
    launch_gemm(hc16, wl + WT_QKV, fl + FB_QKV, nullptr, qkv16, RC, 256, 768, 1 | 8, stream);
    sa_attn_mfma<<<dim3(NCTX / 64, NHEAD, MB * NSPLIT), 256, 0, stream>>>(qkv16, opart16, lbuf);
    gemm_womerge<<<dim3(4, RC / 64), 256, 0, stream>>>(opart16, lbuf, wl + WT_WO, zc_src, zc);
    ln_norm<<<RC / 4, 256, 0, stream>>>(zc, hc16, RC);
    launch_gemm(hc16, wl + WT_W1, fl + FB_W1, nullptr, qkv16, RC, 256, 512, 1 | 2 | 8, stream);
    launch_gemm(qkv16, wl + WT_W2, sa_b2 + l * DMODEL, zc, zc, RC, 512, 256, 1 | 4, stream);

    // ---------- cross-attention block on zt ----------
    // one dispatch normalizes zc (post-FFN; shared by ca_wkv + next-layer qkv) AND zt_src
    ln_norm2<<<(RC + RT) / 4, 256, 0, stream>>>(zc, hc16, RC, zt_src, ht16);
    gemm_wkvq<<<dim3(8, RT / 64, 2), 256, 0, stream>>>(
        hc16, wl + WT_CWKV, fl + FB_WKV, qkvb,
        ht16, wl + WT_CWQ,  fl + FB_WQ,  qb);
    ca_attn_kernel<<<RT, 256, 0, stream>>>(qb, qkvb, idxb, maskb, ob16);
    launch_gemm(ob16, wl + WT_CWO, nullptr, zt_src, zt, RT, 256, 256, 4, stream);
    ln_norm<<<RT / 4, 256, 0, stream>>>(zt, ht16, RT);
    launch_gemm(ht16, wl + WT_CW1, fl + FB_CW1, nullptr, qkv16, RT, 256, 512, 1 | 2 | 8, stream);
    launch_gemm(qkv16, wl + WT_CW2, ca_b2 + l * DMODEL, zt, zt, RT, 512, 256, 1 | 4, stream);
  }
}

// Round 18
// 360.691 us; speedup vs baseline: 1.0879x; 1.0879x over previous
//
#include <hip/hip_runtime.h>
#include <math.h>

// ---------------- problem constants ----------------
#define LAYERS 2
#define DMODEL 256
#define NHEAD  8
#define DHEAD  32
#define FF     512
#define KNB    9
#define MB     4
#define G1D    40
#define G2D    40
#define NTGT   2048
#define NCTX   1600          // G1D*G2D
#define RC     (MB*NCTX)     // 6400 grid rows
#define RT     (MB*NTGT)     // 8192 target rows
#define NSPLIT 4             // sa_attn key-split factor

typedef __attribute__((ext_vector_type(8))) short short8;   // 8 bf16 (4 VGPRs)
typedef __attribute__((ext_vector_type(4))) float f32x4;    // mfma C/D

#if __has_builtin(__builtin_amdgcn_exp2f)
#define EXP2(x) __builtin_amdgcn_exp2f(x)
#else
#define EXP2(x) exp2f(x)
#endif
#define L2E 1.4426950408889634f
#define ATTN_SCALE 0.17677669529663687f   // 1/sqrt(32)

// ---------------- workspace layout (float offsets) ----------------
#define ZC_OFF    0
#define HC_OFF    1638400                      // bf16 normalize(zc): 819200 f
#define HT_OFF    (HC_OFF + 819200)            // bf16 normalize(zt) / SA merged out
#define QKV_OFF   (HC_OFF + 2097152)
#define WT_OFF    (QKV_OFF + 3400000)          // bf16 wT (tail of QKV region)
#define FB_OFF    (QKV_OFF + 4500000)          // folded biases
#define Q_OFF     (QKV_OFF + 4915200)          // CA q fp32
#define O_OFF     (Q_OFF + 2097152)            // CA out bf16
#define IDX_OFF   (O_OFF + 2097152)
#define MASK_OFF  (IDX_OFF + 73728)
#define OPART_OFF (MASK_OFF + 73728)           // SA O-partials: NSPLIT*RC*256 bf16
#define LB_OFF    (OPART_OFF + 3276800)        // SA l-partials: NSPLIT*RC*8 f
#define WS_FLOATS (LB_OFF + 204800)

// per-layer wT offsets (shorts)
#define WT_LAYER   1048576
#define WT_QKV     0
#define WT_WO      196608
#define WT_W1      262144
#define WT_W2      393216
#define WT_CWQ     524288
#define WT_CWKV    589824
#define WT_CWO     720896
#define WT_CW1     786432
#define WT_CW2     917504
// per-layer folded-bias offsets (floats), layer stride 2560
#define FB_LAYER   2560
#define FB_QKV     0
#define FB_W1      768
#define FB_WKV     1280
#define FB_WQ      1792
#define FB_CW1     2048

static __device__ __forceinline__ float gelu_f(float x){
  float t = tanhf(0.7978845608028654f * (x + 0.044715f * x * x * x));
  return 0.5f * x * (1.0f + t);
}
static __device__ __forceinline__ unsigned int bf16_rne(float x){
  unsigned int u = __float_as_uint(x);
  return (u + 0x7fffu + ((u >> 16) & 1u)) >> 16;
}
static __device__ __forceinline__ unsigned int pack_bf16x2(float lo, float hi){
  return bf16_rne(lo) | (bf16_rne(hi) << 16);
}
static __device__ __forceinline__ float bfu(unsigned int u16){
  return __uint_as_float(u16 << 16);
}

// ------ weight prep: fp32 [K][N] -> bf16 [N][K], row-scaled by gamma, col-scaled -----
struct TDesc { const float* src; const float* gamma; int dstoff; int K; int N; int nse; float nsc; };
struct TTable { TDesc e[18]; };

__global__ __launch_bounds__(256)
void wprep_kernel(TTable t, unsigned short* __restrict__ wt){
  TDesc d = t.e[blockIdx.z];
  int n0 = blockIdx.x * 32, k0 = blockIdx.y * 32;
  if (n0 >= d.N || k0 >= d.K) return;
  __shared__ float tile[32][33];
  int tx = threadIdx.x, ty = threadIdx.y;
  float csc = (n0 + tx < d.nse) ? d.nsc : 1.0f;
  #pragma unroll
  for (int j = 0; j < 4; j++){
    int k = k0 + ty * 4 + j;
    float v = d.src[(size_t)k * d.N + n0 + tx];
    if (d.gamma) v *= d.gamma[k];
    tile[ty * 4 + j][tx] = v * csc;
  }
  __syncthreads();
  #pragma unroll
  for (int j = 0; j < 4; j++)
    wt[(size_t)d.dstoff + (size_t)(n0 + ty * 4 + j) * d.K + k0 + tx] =
        (unsigned short)bf16_rne(tile[tx][ty * 4 + j]);
}

// ---------------- bias fold (parallel): fb[n] = (base[n] + sum_k beta[k]*W[k][n])*sc -
struct BDesc { const float* W; const float* beta; const float* base; int outoff; int N; int nse; float nsc; };
struct BTable { BDesc e[10]; };

__global__ __launch_bounds__(256)
void bfold_kernel(BTable t, float* __restrict__ fb){
  BDesc d = t.e[blockIdx.x];
  int n = blockIdx.y * 64 + (threadIdx.x >> 2);
  int q = threadIdx.x & 3;
  if (n >= d.N) return;
  float s = 0.f;
  #pragma unroll 4
  for (int k = q * 64; k < q * 64 + 64; k++)
    s += d.beta[k] * d.W[(size_t)k * d.N + n];
  s += __shfl_xor(s, 1);
  s += __shfl_xor(s, 2);
  if (q == 0){
    float r = s + (d.base ? d.base[n] : 0.f);
    if (n < d.nse) r *= d.nsc;
    fb[d.outoff + n] = r;
  }
}

// ---------------- nearest-grid-neighbour index/mask precompute ----------------
__global__ void nn_idx_kernel(const float* __restrict__ xc, const float* __restrict__ xt,
                              int* __restrict__ idx, float* __restrict__ mask){
  int g = blockIdx.x * blockDim.x + threadIdx.x;
  if (g >= MB * NTGT) return;
  int m = g >> 11;
  float x0 = xt[(size_t)g * 2 + 0];
  float x1 = xt[(size_t)g * 2 + 1];
  const float* xcm = xc + (size_t)m * G1D * G2D * 2;
  int n0 = 0; float b0 = 1e30f;
  for (int i = 0; i < G1D; i++){
    float d = fabsf(x0 - xcm[i * (G2D * 2)]);
    if (d < b0){ b0 = d; n0 = i; }
  }
  int n1 = 0; float b1 = 1e30f;
  for (int j = 0; j < G2D; j++){
    float d = fabsf(x1 - xcm[j * 2 + 1]);
    if (d < b1){ b1 = d; n1 = j; }
  }
  #pragma unroll
  for (int a = 0; a < 3; a++){
    int r0 = n0 + a - 1;
    bool v0 = (r0 >= 0) && (r0 < G1D);
    int i0 = min(max(r0, 0), G1D - 1);
    #pragma unroll
    for (int b = 0; b < 3; b++){
      int r1 = n1 + b - 1;
      bool v1 = (r1 >= 0) && (r1 < G2D);
      int i1 = min(max(r1, 0), G2D - 1);
      idx [(size_t)g * KNB + a * 3 + b] = i0 * G2D + i1;
      mask[(size_t)g * KNB + a * 3 + b] = (v0 && v1) ? 1.0f : 0.0f;
    }
  }
}

// ---------------- LayerNorm normalize-only, bf16 out (single + dual-tensor) ----------
static __device__ __forceinline__ void ln_row(const float* __restrict__ xr,
                                              unsigned short* __restrict__ yr, int lane){
  int d0 = lane * 4;
  float4 xv = *(const float4*)(xr + d0);
  float s = xv.x + xv.y + xv.z + xv.w;
  #pragma unroll
  for (int off = 32; off > 0; off >>= 1) s += __shfl_xor(s, off);
  float mu = s * (1.0f / DMODEL);
  float dx0 = xv.x - mu, dx1 = xv.y - mu, dx2 = xv.z - mu, dx3 = xv.w - mu;
  float v = dx0*dx0 + dx1*dx1 + dx2*dx2 + dx3*dx3;
  #pragma unroll
  for (int off = 32; off > 0; off >>= 1) v += __shfl_xor(v, off);
  float rs = rsqrtf(v * (1.0f / DMODEL) + 1e-5f);
  uint2 w;
  w.x = pack_bf16x2(dx0 * rs, dx1 * rs);
  w.y = pack_bf16x2(dx2 * rs, dx3 * rs);
  *(uint2*)(yr + d0) = w;
}

__global__ __launch_bounds__(256)
void ln_norm(const float* __restrict__ x, unsigned short* __restrict__ y, int rows){
  int gw   = blockIdx.x * 4 + (threadIdx.x >> 6);
  int lane = threadIdx.x & 63;
  if (gw >= rows) return;
  ln_row(x + (size_t)gw * DMODEL, y + (size_t)gw * DMODEL, lane);
}

// dual: rows [0,ra) from xa->ya; rows [ra, ...) from xb->yb
__global__ __launch_bounds__(256)
void ln_norm2(const float* __restrict__ xa, unsigned short* __restrict__ ya, int ra,
              const float* __restrict__ xb, unsigned short* __restrict__ yb){
  int gw   = blockIdx.x * 4 + (threadIdx.x >> 6);
  int lane = threadIdx.x & 63;
  if (gw < ra)
    ln_row(xa + (size_t)gw * DMODEL, ya + (size_t)gw * DMODEL, lane);
  else {
    int g2 = gw - ra;
    ln_row(xb + (size_t)g2 * DMODEL, yb + (size_t)g2 * DMODEL, lane);
  }
}

// ================= MFMA GEMM, templated tile (MTxNT), BK=64 dbuf, glds staging ======
template<int ROWS>
static __device__ __forceinline__ void stage_glds(const unsigned short* __restrict__ src,
                                                  int Ksrc, unsigned short* lds,
                                                  int wave, int lane){
  #pragma unroll
  for (int j = 0; j < ROWS / 32; j++){
    int ublk = (j * 4 + wave) * 64;          // wave-uniform first 16B-unit
    int u    = ublk + lane;
    int row  = u >> 3;                       // 8 units (128B) per row
    int unit = (u & 7) ^ (row & 7);          // source pre-swizzle
    __builtin_amdgcn_global_load_lds(
        (const __attribute__((address_space(1))) void*)(src + (size_t)row * Ksrc + unit * 8),
        (__attribute__((address_space(3))) void*)(lds + (size_t)ublk * 8),
        16, 0, 0);
  }
}

template<int K, int MT, int NT>
__global__ __launch_bounds__(256)
void gemm_glds(const unsigned short* __restrict__ A, const unsigned short* __restrict__ Wt,
               const float* __restrict__ bias, const float* __restrict__ res,
               void* __restrict__ C, int N, int flags){
  const int MFR = MT / 32, NFR = NT / 32;    // 16x16 frags per wave
  __shared__ unsigned short Als[2][MT * 64];
  __shared__ unsigned short Bls[2][NT * 64];
  int tid = threadIdx.x;
  int wave = tid >> 6, lane = tid & 63;
  int wm = wave >> 1, wn = wave & 1;
  int l16 = lane & 15, grp = lane >> 4;
  int r0 = blockIdx.y * MT, c0 = blockIdx.x * NT;

  const unsigned short* Ag = A  + (size_t)r0 * K;
  const unsigned short* Bg = Wt + (size_t)c0 * K;
  const int nch = K >> 6;

  stage_glds<MT>(Ag, K, Als[0], wave, lane);
  stage_glds<NT>(Bg, K, Bls[0], wave, lane);

  f32x4 acc[MFR][NFR];
  #pragma unroll
  for (int m = 0; m < MFR; m++)
    #pragma unroll
    for (int n = 0; n < NFR; n++) acc[m][n] = (f32x4){0.f, 0.f, 0.f, 0.f};

  #pragma unroll
  for (int ch = 0; ch < nch; ch++){
    int b = ch & 1;
    __syncthreads();
    if (ch + 1 < nch){
      stage_glds<MT>(Ag + (ch + 1) * 64, K, Als[b ^ 1], wave, lane);
      stage_glds<NT>(Bg + (ch + 1) * 64, K, Bls[b ^ 1], wave, lane);
    }
    const unsigned short* Ab = Als[b];
    const unsigned short* Bb = Bls[b];
    #pragma unroll
    for (int kk = 0; kk < 2; kk++){
      short8 af[MFR], bfr[NFR];
      #pragma unroll
      for (int m = 0; m < MFR; m++){
        int row = wm * (MT / 2) + m * 16 + l16;
        int unit = (kk * 4 + grp) ^ (row & 7);
        af[m] = *(const short8*)(Ab + row * 64 + unit * 8);
      }
      #pragma unroll
      for (int n = 0; n < NFR; n++){
        int row = wn * (NT / 2) + n * 16 + l16;
        int unit = (kk * 4 + grp) ^ (row & 7);
        bfr[n] = *(const short8*)(Bb + row * 64 + unit * 8);
      }
      #pragma unroll
      for (int m = 0; m < MFR; m++)
        #pragma unroll
        for (int n = 0; n < NFR; n++)
          acc[m][n] = __builtin_amdgcn_mfma_f32_16x16x32_bf16(af[m], bfr[n], acc[m][n], 0, 0, 0);
    }
  }

  #pragma unroll
  for (int n = 0; n < NFR; n++){
    int gc = c0 + wn * (NT / 2) + n * 16 + l16;
    float bv = (flags & 1) ? bias[gc] : 0.f;
    #pragma unroll
    for (int m = 0; m < MFR; m++){
      int grb = r0 + wm * (MT / 2) + m * 16 + grp * 4;
      #pragma unroll
      for (int r = 0; r < 4; r++){
        float v = acc[m][n][r] + bv;
        if (flags & 2) v = gelu_f(v);
        if (flags & 4) v += res[(size_t)(grb + r) * N + gc];
        if (flags & 8) ((unsigned short*)C)[(size_t)(grb + r) * N + gc] = (unsigned short)bf16_rne(v);
        else           ((float*)C)[(size_t)(grb + r) * N + gc] = v;
      }
    }
  }
}

// ------- batched wkv (z=0) + wq (z=1) GEMM: both K=256, tile 64x64, bias, fp32 out --
__global__ __launch_bounds__(256)
void gemm_wkvq(const unsigned short* __restrict__ A0, const unsigned short* __restrict__ W0,
               const float* __restrict__ b0, float* __restrict__ C0,
               const unsigned short* __restrict__ A1, const unsigned short* __restrict__ W1,
               const float* __restrict__ b1, float* __restrict__ C1){
  int z = blockIdx.z;
  int N = z ? 256 : 512;
  int R = z ? RT : RC;
  if ((int)blockIdx.x * 64 >= N || (int)blockIdx.y * 64 >= R) return;
  const unsigned short* A  = z ? A1 : A0;
  const unsigned short* Wt = z ? W1 : W0;
  const float* bias        = z ? b1 : b0;
  float* C                 = z ? C1 : C0;

  __shared__ unsigned short Als[2][64 * 64];
  __shared__ unsigned short Bls[2][64 * 64];
  int tid = threadIdx.x;
  int wave = tid >> 6, lane = tid & 63;
  int wm = wave >> 1, wn = wave & 1;
  int l16 = lane & 15, grp = lane >> 4;
  int r0 = blockIdx.y * 64, c0 = blockIdx.x * 64;

  const unsigned short* Ag = A  + (size_t)r0 * 256;
  const unsigned short* Bg = Wt + (size_t)c0 * 256;

  stage_glds<64>(Ag, 256, Als[0], wave, lane);
  stage_glds<64>(Bg, 256, Bls[0], wave, lane);

  f32x4 acc[2][2];
  #pragma unroll
  for (int m = 0; m < 2; m++)
    #pragma unroll
    for (int n = 0; n < 2; n++) acc[m][n] = (f32x4){0.f, 0.f, 0.f, 0.f};

  #pragma unroll
  for (int ch = 0; ch < 4; ch++){
    int b = ch & 1;
    __syncthreads();
    if (ch + 1 < 4){
      stage_glds<64>(Ag + (ch + 1) * 64, 256, Als[b ^ 1], wave, lane);
      stage_glds<64>(Bg + (ch + 1) * 64, 256, Bls[b ^ 1], wave, lane);
    }
    const unsigned short* Ab = Als[b];
    const unsigned short* Bb = Bls[b];
    #pragma unroll
    for (int kk = 0; kk < 2; kk++){
      short8 af[2], bfr[2];
      #pragma unroll
      for (int m = 0; m < 2; m++){
        int row = wm * 32 + m * 16 + l16;
        int unit = (kk * 4 + grp) ^ (row & 7);
        af[m] = *(const short8*)(Ab + row * 64 + unit * 8);
      }
      #pragma unroll
      for (int n = 0; n < 2; n++){
        int row = wn * 32 + n * 16 + l16;
        int unit = (kk * 4 + grp) ^ (row & 7);
        bfr[n] = *(const short8*)(Bb + row * 64 + unit * 8);
      }
      #pragma unroll
      for (int m = 0; m < 2; m++)
        #pragma unroll
        for (int n = 0; n < 2; n++)
          acc[m][n] = __builtin_amdgcn_mfma_f32_16x16x32_bf16(af[m], bfr[n], acc[m][n], 0, 0, 0);
    }
  }

  #pragma unroll
  for (int n = 0; n < 2; n++){
    int gc = c0 + wn * 32 + n * 16 + l16;
    float bv = bias[gc];
    #pragma unroll
    for (int m = 0; m < 2; m++){
      int grb = r0 + wm * 32 + m * 16 + grp * 4;
      #pragma unroll
      for (int r = 0; r < 4; r++)
        C[(size_t)(grb + r) * N + gc] = acc[m][n][r] + bv;
    }
  }
}

// ------- self-attention: bf16 MFMA flash, KEY-SPLIT x4, FIXED-SHIFT softmax ---------
#define KSTR 40
#define VSTR 70
#define PSTR 72
__global__ __launch_bounds__(256)
void sa_attn_mfma(const unsigned short* __restrict__ qkv,
                  unsigned short* __restrict__ opart, float* __restrict__ lb){
  int mz = blockIdx.z;
  int m = mz & 3, split = mz >> 2;           // split 0..3
  int h = blockIdx.y;
  int tid  = threadIdx.x;
  int wave = tid >> 6, lane = tid & 63;
  int qr = lane & 15, grp = lane >> 4;
  int q0 = blockIdx.x * 64 + wave * 16;

  int kt0 = split ? (7 + (split - 1) * 6) : 0;
  int kt1 = kt0 + (split ? 6 : 7);

  __shared__ unsigned short Kls[2][64 * KSTR];
  __shared__ unsigned short Vls[2][32 * VSTR];
  __shared__ unsigned short Pls[4][16 * PSTR];
  unsigned short* Pw = Pls[wave];

  short8 qf = *(const short8*)(qkv + ((size_t)(m * NCTX + q0 + qr)) * 768 + h * 32 + grp * 8);

  int skey = tid >> 2;
  int scol = (tid & 3) * 8;
  const unsigned short* kbase = qkv + (size_t)m * NCTX * 768 + 256 + h * 32 + scol;

  uint4 kreg = *(const uint4*)(kbase + (size_t)(kt0 * 64 + skey) * 768);
  uint4 vreg = *(const uint4*)(kbase + (size_t)(kt0 * 64 + skey) * 768 + 256);

  float lq = 0.0f;                       // per-thread partial sum of P
  f32x4 acc0 = {0.f, 0.f, 0.f, 0.f};
  f32x4 acc1 = {0.f, 0.f, 0.f, 0.f};

  {
    *(uint4*)&Kls[0][skey * KSTR + scol] = kreg;
    unsigned int vv[4] = {vreg.x, vreg.y, vreg.z, vreg.w};
    #pragma unroll
    for (int j = 0; j < 4; j++){
      Vls[0][(scol + 2 * j    ) * VSTR + skey] = (unsigned short)(vv[j] & 0xffffu);
      Vls[0][(scol + 2 * j + 1) * VSTR + skey] = (unsigned short)(vv[j] >> 16);
    }
  }

  for (int kt = kt0; kt < kt1; kt++){
    int b = (kt - kt0) & 1;
    __syncthreads();
    if (kt + 1 < kt1){
      kreg = *(const uint4*)(kbase + (size_t)((kt + 1) * 64 + skey) * 768);
      vreg = *(const uint4*)(kbase + (size_t)((kt + 1) * 64 + skey) * 768 + 256);
    }

    f32x4 s0 = {0.f,0.f,0.f,0.f}, s1 = {0.f,0.f,0.f,0.f};
    f32x4 s2 = {0.f,0.f,0.f,0.f}, s3 = {0.f,0.f,0.f,0.f};
    {
      const short8 k0 = *(const short8*)&Kls[b][( 0 + qr) * KSTR + grp * 8];
      const short8 k1 = *(const short8*)&Kls[b][(16 + qr) * KSTR + grp * 8];
      const short8 k2 = *(const short8*)&Kls[b][(32 + qr) * KSTR + grp * 8];
      const short8 k3 = *(const short8*)&Kls[b][(48 + qr) * KSTR + grp * 8];
      s0 = __builtin_amdgcn_mfma_f32_16x16x32_bf16(k0, qf, s0, 0, 0, 0);
      s1 = __builtin_amdgcn_mfma_f32_16x16x32_bf16(k1, qf, s1, 0, 0, 0);
      s2 = __builtin_amdgcn_mfma_f32_16x16x32_bf16(k2, qf, s2, 0, 0, 0);
      s3 = __builtin_amdgcn_mfma_f32_16x16x32_bf16(k3, qf, s3, 0, 0, 0);
    }

    float p[4][4];
    #pragma unroll
    for (int r = 0; r < 4; r++){
      p[0][r] = EXP2(s0[r]); p[1][r] = EXP2(s1[r]);
      p[2][r] = EXP2(s2[r]); p[3][r] = EXP2(s3[r]);
    }
    #pragma unroll
    for (int kb = 0; kb < 4; kb++)
      #pragma unroll
      for (int r = 0; r < 4; r++) lq += p[kb][r];

    #pragma unroll
    for (int kb = 0; kb < 4; kb++){
      *(unsigned int*)&Pw[qr * PSTR + kb * 16 + grp * 4]     = pack_bf16x2(p[kb][0], p[kb][1]);
      *(unsigned int*)&Pw[qr * PSTR + kb * 16 + grp * 4 + 2] = pack_bf16x2(p[kb][2], p[kb][3]);
    }

    #pragma unroll
    for (int hh = 0; hh < 2; hh++){
      const short8 pf = *(const short8*)&Pw[qr * PSTR + hh * 32 + grp * 8];
      const short8 v0 = *(const short8*)&Vls[b][( 0 + qr) * VSTR + hh * 32 + grp * 8];
      const short8 v1 = *(const short8*)&Vls[b][(16 + qr) * VSTR + hh * 32 + grp * 8];
      acc0 = __builtin_amdgcn_mfma_f32_16x16x32_bf16(v0, pf, acc0, 0, 0, 0);
      acc1 = __builtin_amdgcn_mfma_f32_16x16x32_bf16(v1, pf, acc1, 0, 0, 0);
    }

    if (kt + 1 < kt1){
      *(uint4*)&Kls[b ^ 1][skey * KSTR + scol] = kreg;
      unsigned int vv[4] = {vreg.x, vreg.y, vreg.z, vreg.w};
      #pragma unroll
      for (int j = 0; j < 4; j++){
        Vls[b ^ 1][(scol + 2 * j    ) * VSTR + skey] = (unsigned short)(vv[j] & 0xffffu);
        Vls[b ^ 1][(scol + 2 * j + 1) * VSTR + skey] = (unsigned short)(vv[j] >> 16);
      }
    }
  }

  lq += __shfl_xor(lq, 16);
  lq += __shfl_xor(lq, 32);
  float inv = 1.0f / lq;
  int gr = m * NCTX + q0 + qr;
  unsigned short* op = opart + ((size_t)(split * RC + gr)) * DMODEL + h * DHEAD;
  uint2 o16a, o16b;
  o16a.x = pack_bf16x2(acc0[0] * inv, acc0[1] * inv);
  o16a.y = pack_bf16x2(acc0[2] * inv, acc0[3] * inv);
  o16b.x = pack_bf16x2(acc1[0] * inv, acc1[1] * inv);
  o16b.y = pack_bf16x2(acc1[2] * inv, acc1[3] * inv);
  *(uint2*)(op + grp * 4)      = o16a;
  *(uint2*)(op + 16 + grp * 4) = o16b;
  if (grp == 0)
    lb[((size_t)(split * RC + gr)) * 8 + h] = lq;
}

// ------- key-split merge (4-way): out = sum_i l_i*O_i / sum_i l_i -------------------
__global__ __launch_bounds__(256)
void sa_merge(const unsigned short* __restrict__ opart, const float* __restrict__ lb,
              unsigned short* __restrict__ out){
  int g = blockIdx.x * 256 + threadIdx.x;   // over RC*64 (4 dims each)
  int gr = g >> 6;
  int d4 = (g & 63) * 4;
  int h  = d4 >> 5;
  float l[NSPLIT];
  float lsum = 0.f;
  #pragma unroll
  for (int s = 0; s < NSPLIT; s++){
    l[s] = lb[(size_t)(s * RC + gr) * 8 + h];
    lsum += l[s];
  }
  float inv = 1.0f / lsum;
  float o0 = 0.f, o1 = 0.f, o2 = 0.f, o3 = 0.f;
  #pragma unroll
  for (int s = 0; s < NSPLIT; s++){
    float w = l[s] * inv;
    uint2 a = *(const uint2*)(opart + (size_t)(s * RC + gr) * DMODEL + d4);
    o0 += bfu(a.x & 0xffffu) * w;
    o1 += bfu(a.x >> 16)     * w;
    o2 += bfu(a.y & 0xffffu) * w;
    o3 += bfu(a.y >> 16)     * w;
  }
  uint2 w;
  w.x = pack_bf16x2(o0, o1);
  w.y = pack_bf16x2(o2, o3);
  *(uint2*)(out + (size_t)gr * DMODEL + d4) = w;
}

// ------- cross-attention over 9 gathered neighbours (q pre-scaled at wprep) ---------
__global__ __launch_bounds__(256)
void ca_attn_kernel(const float* __restrict__ qb, const float* __restrict__ kv,
                    const int* __restrict__ idx, const float* __restrict__ mask,
                    unsigned short* __restrict__ ob){
  int g = blockIdx.x;
  int m = g >> 11;
  int tid = threadIdx.x;
  float q = qb[(size_t)g * DMODEL + tid];
  float s[KNB];
  int rws[KNB];
  #pragma unroll
  for (int k = 0; k < KNB; k++){
    int row = idx[(size_t)g * KNB + k];
    rws[k] = row;
    float p = q * kv[((size_t)(m * NCTX + row)) * 512 + tid];
    #pragma unroll
    for (int off = 16; off > 0; off >>= 1) p += __shfl_xor(p, off, 32);
    s[k] = (mask[(size_t)g * KNB + k] > 0.5f) ? p : -1e30f;
  }
  float sm = s[0];
  #pragma unroll
  for (int k = 1; k < KNB; k++) sm = fmaxf(sm, s[k]);
  float den = 0.f, w[KNB];
  #pragma unroll
  for (int k = 0; k < KNB; k++){ w[k] = __expf(s[k] - sm); den += w[k]; }
  float inv = 1.0f / den;
  float o = 0.f;
  #pragma unroll
  for (int k = 0; k < KNB; k++)
    o += w[k] * kv[((size_t)(m * NCTX + rws[k])) * 512 + 256 + tid];
  ob[(size_t)g * DMODEL + tid] = (unsigned short)bf16_rne(o * inv);
}

// ---------------- host launch helper ----------------
static inline void launch_gemm(const unsigned short* A, const unsigned short* Wt,
                               const float* bias, const float* res, void* C,
                               int R, int K, int N, int flags, hipStream_t stream){
  if (N == 768){
    gemm_glds<256, 64, 128><<<dim3(N / 128, R / 64), 256, 0, stream>>>(A, Wt, bias, res, C, N, flags);
  } else if (K == 256){
    gemm_glds<256, 64, 64><<<dim3(N / 64, R / 64), 256, 0, stream>>>(A, Wt, bias, res, C, N, flags);
  } else {
    gemm_glds<512, 64, 64><<<dim3(N / 64, R / 64), 256, 0, stream>>>(A, Wt, bias, res, C, N, flags);
  }
}

// ---------------- host launcher ----------------
extern "C" void kernel_launch(void* const* d_in, const int* in_sizes, int n_in,
                              void* d_out, int out_size, void* d_ws, size_t ws_size,
                              hipStream_t stream){
  const float* xc      = (const float*)d_in[0];
  const float* zc_in   = (const float*)d_in[1];
  const float* xt      = (const float*)d_in[2];
  const float* zt_in   = (const float*)d_in[3];
  const float* sa_wqkv = (const float*)d_in[4];
  const float* sa_wo   = (const float*)d_in[5];
  const float* sa_ln1  = (const float*)d_in[6];
  const float* sa_ln2  = (const float*)d_in[7];
  const float* sa_w1   = (const float*)d_in[8];
  const float* sa_b1   = (const float*)d_in[9];
  const float* sa_w2   = (const float*)d_in[10];
  const float* sa_b2   = (const float*)d_in[11];
  const float* ca_wq   = (const float*)d_in[12];
  const float* ca_wkv  = (const float*)d_in[13];
  const float* ca_wo   = (const float*)d_in[14];
  const float* ca_lnq  = (const float*)d_in[15];
  const float* ca_lnkv = (const float*)d_in[16];
  const float* ca_ln2  = (const float*)d_in[17];
  const float* ca_w1   = (const float*)d_in[18];
  const float* ca_b1   = (const float*)d_in[19];
  const float* ca_w2   = (const float*)d_in[20];
  const float* ca_b2   = (const float*)d_in[21];

  if (ws_size < (size_t)WS_FLOATS * sizeof(float)) return;
  float* ws    = (float*)d_ws;
  float* zc    = ws + ZC_OFF;
  unsigned short* hc16 = (unsigned short*)(ws + HC_OFF);   // normalize(zc) bf16
  unsigned short* ht16 = (unsigned short*)(ws + HT_OFF);   // normalize(zt) / SA merged out
  float* qkvb  = ws + QKV_OFF;   // aliased: bf16 qkv / fp32 CA kv / bf16 ffn-mid
  unsigned short* qkv16 = (unsigned short*)qkvb;
  unsigned short* wt    = (unsigned short*)(ws + WT_OFF);
  float* fb    = ws + FB_OFF;
  float* qb    = ws + Q_OFF;                               // CA q
  unsigned short* ob16    = (unsigned short*)(ws + O_OFF); // CA out
  unsigned short* opart16 = (unsigned short*)(ws + OPART_OFF);
  float* lbuf  = ws + LB_OFF;
  int*   idxb  = (int*)(ws + IDX_OFF);
  float* maskb = ws + MASK_OFF;
  float* zt    = (float*)d_out;

  const float QSC = ATTN_SCALE * L2E;   // folded into sa Q (exp2-domain softmax)

  // ---- weight prep (transpose + gamma row-scale + Q col-scale) ----
  TTable tt;
  for (int l = 0; l < LAYERS; l++){
    int b = l * WT_LAYER, i = l * 9;
    tt.e[i + 0] = { sa_wqkv + (size_t)l * 256 * 768, sa_ln1  + l * 512, b + WT_QKV,  256, 768, 256, QSC };
    tt.e[i + 1] = { sa_wo   + (size_t)l * 256 * 256, nullptr,           b + WT_WO,   256, 256, 0, 1.f };
    tt.e[i + 2] = { sa_w1   + (size_t)l * 256 * 512, sa_ln2  + l * 512, b + WT_W1,   256, 512, 0, 1.f };
    tt.e[i + 3] = { sa_w2   + (size_t)l * 512 * 256, nullptr,           b + WT_W2,   512, 256, 0, 1.f };
    tt.e[i + 4] = { ca_wq   + (size_t)l * 256 * 256, ca_lnq  + l * 512, b + WT_CWQ,  256, 256, 256, ATTN_SCALE };
    tt.e[i + 5] = { ca_wkv  + (size_t)l * 256 * 512, ca_lnkv + l * 512, b + WT_CWKV, 256, 512, 0, 1.f };
    tt.e[i + 6] = { ca_wo   + (size_t)l * 256 * 256, nullptr,           b + WT_CWO,  256, 256, 0, 1.f };
    tt.e[i + 7] = { ca_w1   + (size_t)l * 256 * 512, ca_ln2  + l * 512, b + WT_CW1,  256, 512, 0, 1.f };
    tt.e[i + 8] = { ca_w2   + (size_t)l * 512 * 256, nullptr,           b + WT_CW2,  512, 256, 0, 1.f };
  }
  wprep_kernel<<<dim3(24, 16, 18), dim3(32, 8), 0, stream>>>(tt, wt);

  // ---- beta fold into biases (parallel; Q-part scaled to match) ----
  BTable bt;
  for (int l = 0; l < LAYERS; l++){
    int fo = l * FB_LAYER, i = l * 5;
    bt.e[i + 0] = { sa_wqkv + (size_t)l * 256 * 768, sa_ln1  + l * 512 + 256, nullptr,        fo + FB_QKV, 768, 256, QSC };
    bt.e[i + 1] = { sa_w1   + (size_t)l * 256 * 512, sa_ln2  + l * 512 + 256, sa_b1 + l * FF, fo + FB_W1,  512, 0, 1.f };
    bt.e[i + 2] = { ca_wkv  + (size_t)l * 256 * 512, ca_lnkv + l * 512 + 256, nullptr,        fo + FB_WKV, 512, 0, 1.f };
    bt.e[i + 3] = { ca_wq   + (size_t)l * 256 * 256, ca_lnq  + l * 512 + 256, nullptr,        fo + FB_WQ,  256, 256, ATTN_SCALE };
    bt.e[i + 4] = { ca_w1   + (size_t)l * 256 * 512, ca_ln2  + l * 512 + 256, ca_b1 + l * FF, fo + FB_CW1, 512, 0, 1.f };
  }
  bfold_kernel<<<dim3(10, 12), 256, 0, stream>>>(bt, fb);

  nn_idx_kernel<<<(MB * NTGT) / 256, 256, 0, stream>>>(xc, xt, idxb, maskb);

  // upfront normalize(zc); post-FFN normalize is shared by ca_wkv and next-layer qkv
  ln_norm<<<RC / 4, 256, 0, stream>>>(zc_in, hc16, RC);

  for (int l = 0; l < LAYERS; l++){
    const unsigned short* wl = wt + (size_t)l * WT_LAYER;
    const float* fl = fb + (size_t)l * FB_LAYER;
    const float* zc_src = (l == 0) ? zc_in : zc;
    const float* zt_src = (l == 0) ? zt_in : zt;

    // ---------- self-attention block on zc ----------
    launch_gemm(hc16, wl + WT_QKV, fl + FB_QKV, nullptr, qkv16, RC, 256, 768, 1 | 8, stream);
    sa_attn_mfma<<<dim3(NCTX / 64, NHEAD, MB * NSPLIT), 256, 0, stream>>>(qkv16, opart16, lbuf);
    sa_merge<<<RC * 64 / 256, 256, 0, stream>>>(opart16, lbuf, ht16);
    launch_gemm(ht16, wl + WT_WO, nullptr, zc_src, zc, RC, 256, 256, 4, stream);
    ln_norm<<<RC / 4, 256, 0, stream>>>(zc, hc16, RC);
    launch_gemm(hc16, wl + WT_W1, fl + FB_W1, nullptr, qkv16, RC, 256, 512, 1 | 2 | 8, stream);
    launch_gemm(qkv16, wl + WT_W2, sa_b2 + l * DMODEL, zc, zc, RC, 512, 256, 1 | 4, stream);

    // ---------- cross-attention block on zt ----------
    // one dispatch normalizes zc (post-FFN; shared by ca_wkv + next-layer qkv) AND zt_src
    ln_norm2<<<(RC + RT) / 4, 256, 0, stream>>>(zc, hc16, RC, zt_src, ht16);
    gemm_wkvq<<<dim3(8, RT / 64, 2), 256, 0, stream>>>(
        hc16, wl + WT_CWKV, fl + FB_WKV, qkvb,
        ht16, wl + WT_CWQ,  fl + FB_WQ,  qb);
    ca_attn_kernel<<<RT, 256, 0, stream>>>(qb, qkvb, idxb, maskb, ob16);
    launch_gemm(ob16, wl + WT_CWO, nullptr, zt_src, zt, RT, 256, 256, 4, stream);
    ln_norm<<<RT / 4, 256, 0, stream>>>(zt, ht16, RT);
    launch_gemm(ht16, wl + WT_CW1, fl + FB_CW1, nullptr, qkv16, RT, 256, 512, 1 | 2 | 8, stream);
    launch_gemm(qkv16, wl + WT_CW2, ca_b2 + l * DMODEL, zt, zt, RT, 512, 256, 1 | 4, stream);
  }
}

// Round 19
// 355.392 us; speedup vs baseline: 1.1041x; 1.0149x over previous
//
#include <hip/hip_runtime.h>
#include <math.h>

// ---------------- problem constants ----------------
#define LAYERS 2
#define DMODEL 256
#define NHEAD  8
#define DHEAD  32
#define FF     512
#define KNB    9
#define MB     4
#define G1D    40
#define G2D    40
#define NTGT   2048
#define NCTX   1600          // G1D*G2D
#define RC     (MB*NCTX)     // 6400 grid rows
#define RT     (MB*NTGT)     // 8192 target rows
#define NSPLIT 4             // sa_attn key-split factor

typedef __attribute__((ext_vector_type(8))) short short8;   // 8 bf16 (4 VGPRs)
typedef __attribute__((ext_vector_type(4))) float f32x4;    // mfma C/D

#if __has_builtin(__builtin_amdgcn_exp2f)
#define EXP2(x) __builtin_amdgcn_exp2f(x)
#else
#define EXP2(x) exp2f(x)
#endif
#define L2E 1.4426950408889634f
#define ATTN_SCALE 0.17677669529663687f   // 1/sqrt(32)

// ---------------- workspace layout (float offsets) ----------------
#define ZC_OFF    0
#define HC_OFF    1638400                      // bf16 normalize(zc): 819200 f
#define HT_OFF    (HC_OFF + 819200)            // bf16 normalize(zt) / SA merged out
#define QKV_OFF   (HC_OFF + 2097152)
#define WT_OFF    (QKV_OFF + 3400000)          // bf16 wT (tail of QKV region)
#define FB_OFF    (QKV_OFF + 4500000)          // folded biases
#define Q_OFF     (QKV_OFF + 4915200)          // CA q bf16
#define O_OFF     (Q_OFF + 2097152)            // CA out bf16
#define IDX_OFF   (O_OFF + 2097152)
#define MASK_OFF  (IDX_OFF + 73728)
#define OPART_OFF (MASK_OFF + 73728)           // SA O-partials: NSPLIT*RC*256 bf16
#define LB_OFF    (OPART_OFF + 3276800)        // SA l-partials: NSPLIT*RC*8 f
#define WS_FLOATS (LB_OFF + 204800)

// per-layer wT offsets (shorts)
#define WT_LAYER   1048576
#define WT_QKV     0
#define WT_WO      196608
#define WT_W1      262144
#define WT_W2      393216
#define WT_CWQ     524288
#define WT_CWKV    589824
#define WT_CWO     720896
#define WT_CW1     786432
#define WT_CW2     917504
// per-layer folded-bias offsets (floats), layer stride 2560
#define FB_LAYER   2560
#define FB_QKV     0
#define FB_W1      768
#define FB_WKV     1280
#define FB_WQ      1792
#define FB_CW1     2048

static __device__ __forceinline__ float gelu_f(float x){
  float t = tanhf(0.7978845608028654f * (x + 0.044715f * x * x * x));
  return 0.5f * x * (1.0f + t);
}
static __device__ __forceinline__ unsigned int bf16_rne(float x){
  unsigned int u = __float_as_uint(x);
  return (u + 0x7fffu + ((u >> 16) & 1u)) >> 16;
}
static __device__ __forceinline__ unsigned int pack_bf16x2(float lo, float hi){
  return bf16_rne(lo) | (bf16_rne(hi) << 16);
}
static __device__ __forceinline__ float bfu(unsigned int u16){
  return __uint_as_float(u16 << 16);
}

// ------ weight prep: fp32 [K][N] -> bf16 [N][K], row-scaled by gamma, col-scaled -----
struct TDesc { const float* src; const float* gamma; int dstoff; int K; int N; int nse; float nsc; };
struct TTable { TDesc e[18]; };

__global__ __launch_bounds__(256)
void wprep_kernel(TTable t, unsigned short* __restrict__ wt){
  TDesc d = t.e[blockIdx.z];
  int n0 = blockIdx.x * 32, k0 = blockIdx.y * 32;
  if (n0 >= d.N || k0 >= d.K) return;
  __shared__ float tile[32][33];
  int tx = threadIdx.x, ty = threadIdx.y;
  float csc = (n0 + tx < d.nse) ? d.nsc : 1.0f;
  #pragma unroll
  for (int j = 0; j < 4; j++){
    int k = k0 + ty * 4 + j;
    float v = d.src[(size_t)k * d.N + n0 + tx];
    if (d.gamma) v *= d.gamma[k];
    tile[ty * 4 + j][tx] = v * csc;
  }
  __syncthreads();
  #pragma unroll
  for (int j = 0; j < 4; j++)
    wt[(size_t)d.dstoff + (size_t)(n0 + ty * 4 + j) * d.K + k0 + tx] =
        (unsigned short)bf16_rne(tile[tx][ty * 4 + j]);
}

// ---------------- bias fold (parallel): fb[n] = (base[n] + sum_k beta[k]*W[k][n])*sc -
struct BDesc { const float* W; const float* beta; const float* base; int outoff; int N; int nse; float nsc; };
struct BTable { BDesc e[10]; };

__global__ __launch_bounds__(256)
void bfold_kernel(BTable t, float* __restrict__ fb){
  BDesc d = t.e[blockIdx.x];
  int n = blockIdx.y * 64 + (threadIdx.x >> 2);
  int q = threadIdx.x & 3;
  if (n >= d.N) return;
  float s = 0.f;
  #pragma unroll 4
  for (int k = q * 64; k < q * 64 + 64; k++)
    s += d.beta[k] * d.W[(size_t)k * d.N + n];
  s += __shfl_xor(s, 1);
  s += __shfl_xor(s, 2);
  if (q == 0){
    float r = s + (d.base ? d.base[n] : 0.f);
    if (n < d.nse) r *= d.nsc;
    fb[d.outoff + n] = r;
  }
}

// ---------------- nearest-grid-neighbour index/mask precompute ----------------
__global__ void nn_idx_kernel(const float* __restrict__ xc, const float* __restrict__ xt,
                              int* __restrict__ idx, float* __restrict__ mask){
  int g = blockIdx.x * blockDim.x + threadIdx.x;
  if (g >= MB * NTGT) return;
  int m = g >> 11;
  float x0 = xt[(size_t)g * 2 + 0];
  float x1 = xt[(size_t)g * 2 + 1];
  const float* xcm = xc + (size_t)m * G1D * G2D * 2;
  int n0 = 0; float b0 = 1e30f;
  for (int i = 0; i < G1D; i++){
    float d = fabsf(x0 - xcm[i * (G2D * 2)]);
    if (d < b0){ b0 = d; n0 = i; }
  }
  int n1 = 0; float b1 = 1e30f;
  for (int j = 0; j < G2D; j++){
    float d = fabsf(x1 - xcm[j * 2 + 1]);
    if (d < b1){ b1 = d; n1 = j; }
  }
  #pragma unroll
  for (int a = 0; a < 3; a++){
    int r0 = n0 + a - 1;
    bool v0 = (r0 >= 0) && (r0 < G1D);
    int i0 = min(max(r0, 0), G1D - 1);
    #pragma unroll
    for (int b = 0; b < 3; b++){
      int r1 = n1 + b - 1;
      bool v1 = (r1 >= 0) && (r1 < G2D);
      int i1 = min(max(r1, 0), G2D - 1);
      idx [(size_t)g * KNB + a * 3 + b] = i0 * G2D + i1;
      mask[(size_t)g * KNB + a * 3 + b] = (v0 && v1) ? 1.0f : 0.0f;
    }
  }
}

// ---------------- LayerNorm normalize-only, bf16 out (single + dual-tensor) ----------
static __device__ __forceinline__ void ln_row(const float* __restrict__ xr,
                                              unsigned short* __restrict__ yr, int lane){
  int d0 = lane * 4;
  float4 xv = *(const float4*)(xr + d0);
  float s = xv.x + xv.y + xv.z + xv.w;
  #pragma unroll
  for (int off = 32; off > 0; off >>= 1) s += __shfl_xor(s, off);
  float mu = s * (1.0f / DMODEL);
  float dx0 = xv.x - mu, dx1 = xv.y - mu, dx2 = xv.z - mu, dx3 = xv.w - mu;
  float v = dx0*dx0 + dx1*dx1 + dx2*dx2 + dx3*dx3;
  #pragma unroll
  for (int off = 32; off > 0; off >>= 1) v += __shfl_xor(v, off);
  float rs = rsqrtf(v * (1.0f / DMODEL) + 1e-5f);
  uint2 w;
  w.x = pack_bf16x2(dx0 * rs, dx1 * rs);
  w.y = pack_bf16x2(dx2 * rs, dx3 * rs);
  *(uint2*)(yr + d0) = w;
}

__global__ __launch_bounds__(256)
void ln_norm(const float* __restrict__ x, unsigned short* __restrict__ y, int rows){
  int gw   = blockIdx.x * 4 + (threadIdx.x >> 6);
  int lane = threadIdx.x & 63;
  if (gw >= rows) return;
  ln_row(x + (size_t)gw * DMODEL, y + (size_t)gw * DMODEL, lane);
}

// dual: rows [0,ra) from xa->ya; rows [ra, ...) from xb->yb
__global__ __launch_bounds__(256)
void ln_norm2(const float* __restrict__ xa, unsigned short* __restrict__ ya, int ra,
              const float* __restrict__ xb, unsigned short* __restrict__ yb){
  int gw   = blockIdx.x * 4 + (threadIdx.x >> 6);
  int lane = threadIdx.x & 63;
  if (gw < ra)
    ln_row(xa + (size_t)gw * DMODEL, ya + (size_t)gw * DMODEL, lane);
  else {
    int g2 = gw - ra;
    ln_row(xb + (size_t)g2 * DMODEL, yb + (size_t)g2 * DMODEL, lane);
  }
}

// ================= MFMA GEMM, templated tile (MTxNT), BK=64 dbuf, glds staging ======
template<int ROWS>
static __device__ __forceinline__ void stage_glds(const unsigned short* __restrict__ src,
                                                  int Ksrc, unsigned short* lds,
                                                  int wave, int lane){
  #pragma unroll
  for (int j = 0; j < ROWS / 32; j++){
    int ublk = (j * 4 + wave) * 64;          // wave-uniform first 16B-unit
    int u    = ublk + lane;
    int row  = u >> 3;                       // 8 units (128B) per row
    int unit = (u & 7) ^ (row & 7);          // source pre-swizzle
    __builtin_amdgcn_global_load_lds(
        (const __attribute__((address_space(1))) void*)(src + (size_t)row * Ksrc + unit * 8),
        (__attribute__((address_space(3))) void*)(lds + (size_t)ublk * 8),
        16, 0, 0);
  }
}

template<int K, int MT, int NT>
__global__ __launch_bounds__(256)
void gemm_glds(const unsigned short* __restrict__ A, const unsigned short* __restrict__ Wt,
               const float* __restrict__ bias, const float* __restrict__ res,
               void* __restrict__ C, int N, int flags){
  const int MFR = MT / 32, NFR = NT / 32;    // 16x16 frags per wave
  __shared__ unsigned short Als[2][MT * 64];
  __shared__ unsigned short Bls[2][NT * 64];
  int tid = threadIdx.x;
  int wave = tid >> 6, lane = tid & 63;
  int wm = wave >> 1, wn = wave & 1;
  int l16 = lane & 15, grp = lane >> 4;
  int r0 = blockIdx.y * MT, c0 = blockIdx.x * NT;

  const unsigned short* Ag = A  + (size_t)r0 * K;
  const unsigned short* Bg = Wt + (size_t)c0 * K;
  const int nch = K >> 6;

  stage_glds<MT>(Ag, K, Als[0], wave, lane);
  stage_glds<NT>(Bg, K, Bls[0], wave, lane);

  f32x4 acc[MFR][NFR];
  #pragma unroll
  for (int m = 0; m < MFR; m++)
    #pragma unroll
    for (int n = 0; n < NFR; n++) acc[m][n] = (f32x4){0.f, 0.f, 0.f, 0.f};

  #pragma unroll
  for (int ch = 0; ch < nch; ch++){
    int b = ch & 1;
    __syncthreads();
    if (ch + 1 < nch){
      stage_glds<MT>(Ag + (ch + 1) * 64, K, Als[b ^ 1], wave, lane);
      stage_glds<NT>(Bg + (ch + 1) * 64, K, Bls[b ^ 1], wave, lane);
    }
    const unsigned short* Ab = Als[b];
    const unsigned short* Bb = Bls[b];
    #pragma unroll
    for (int kk = 0; kk < 2; kk++){
      short8 af[MFR], bfr[NFR];
      #pragma unroll
      for (int m = 0; m < MFR; m++){
        int row = wm * (MT / 2) + m * 16 + l16;
        int unit = (kk * 4 + grp) ^ (row & 7);
        af[m] = *(const short8*)(Ab + row * 64 + unit * 8);
      }
      #pragma unroll
      for (int n = 0; n < NFR; n++){
        int row = wn * (NT / 2) + n * 16 + l16;
        int unit = (kk * 4 + grp) ^ (row & 7);
        bfr[n] = *(const short8*)(Bb + row * 64 + unit * 8);
      }
      #pragma unroll
      for (int m = 0; m < MFR; m++)
        #pragma unroll
        for (int n = 0; n < NFR; n++)
          acc[m][n] = __builtin_amdgcn_mfma_f32_16x16x32_bf16(af[m], bfr[n], acc[m][n], 0, 0, 0);
    }
  }

  #pragma unroll
  for (int n = 0; n < NFR; n++){
    int gc = c0 + wn * (NT / 2) + n * 16 + l16;
    float bv = (flags & 1) ? bias[gc] : 0.f;
    #pragma unroll
    for (int m = 0; m < MFR; m++){
      int grb = r0 + wm * (MT / 2) + m * 16 + grp * 4;
      #pragma unroll
      for (int r = 0; r < 4; r++){
        float v = acc[m][n][r] + bv;
        if (flags & 2) v = gelu_f(v);
        if (flags & 4) v += res[(size_t)(grb + r) * N + gc];
        if (flags & 8) ((unsigned short*)C)[(size_t)(grb + r) * N + gc] = (unsigned short)bf16_rne(v);
        else           ((float*)C)[(size_t)(grb + r) * N + gc] = v;
      }
    }
  }
}

// ------- batched wkv (z=0) + wq (z=1) GEMM: K=256, tile 64x64, bias, bf16 out -------
__global__ __launch_bounds__(256)
void gemm_wkvq(const unsigned short* __restrict__ A0, const unsigned short* __restrict__ W0,
               const float* __restrict__ b0, unsigned short* __restrict__ C0,
               const unsigned short* __restrict__ A1, const unsigned short* __restrict__ W1,
               const float* __restrict__ b1, unsigned short* __restrict__ C1){
  int z = blockIdx.z;
  int N = z ? 256 : 512;
  int R = z ? RT : RC;
  if ((int)blockIdx.x * 64 >= N || (int)blockIdx.y * 64 >= R) return;
  const unsigned short* A  = z ? A1 : A0;
  const unsigned short* Wt = z ? W1 : W0;
  const float* bias        = z ? b1 : b0;
  unsigned short* C        = z ? C1 : C0;

  __shared__ unsigned short Als[2][64 * 64];
  __shared__ unsigned short Bls[2][64 * 64];
  int tid = threadIdx.x;
  int wave = tid >> 6, lane = tid & 63;
  int wm = wave >> 1, wn = wave & 1;
  int l16 = lane & 15, grp = lane >> 4;
  int r0 = blockIdx.y * 64, c0 = blockIdx.x * 64;

  const unsigned short* Ag = A  + (size_t)r0 * 256;
  const unsigned short* Bg = Wt + (size_t)c0 * 256;

  stage_glds<64>(Ag, 256, Als[0], wave, lane);
  stage_glds<64>(Bg, 256, Bls[0], wave, lane);

  f32x4 acc[2][2];
  #pragma unroll
  for (int m = 0; m < 2; m++)
    #pragma unroll
    for (int n = 0; n < 2; n++) acc[m][n] = (f32x4){0.f, 0.f, 0.f, 0.f};

  #pragma unroll
  for (int ch = 0; ch < 4; ch++){
    int b = ch & 1;
    __syncthreads();
    if (ch + 1 < 4){
      stage_glds<64>(Ag + (ch + 1) * 64, 256, Als[b ^ 1], wave, lane);
      stage_glds<64>(Bg + (ch + 1) * 64, 256, Bls[b ^ 1], wave, lane);
    }
    const unsigned short* Ab = Als[b];
    const unsigned short* Bb = Bls[b];
    #pragma unroll
    for (int kk = 0; kk < 2; kk++){
      short8 af[2], bfr[2];
      #pragma unroll
      for (int m = 0; m < 2; m++){
        int row = wm * 32 + m * 16 + l16;
        int unit = (kk * 4 + grp) ^ (row & 7);
        af[m] = *(const short8*)(Ab + row * 64 + unit * 8);
      }
      #pragma unroll
      for (int n = 0; n < 2; n++){
        int row = wn * 32 + n * 16 + l16;
        int unit = (kk * 4 + grp) ^ (row & 7);
        bfr[n] = *(const short8*)(Bb + row * 64 + unit * 8);
      }
      #pragma unroll
      for (int m = 0; m < 2; m++)
        #pragma unroll
        for (int n = 0; n < 2; n++)
          acc[m][n] = __builtin_amdgcn_mfma_f32_16x16x32_bf16(af[m], bfr[n], acc[m][n], 0, 0, 0);
    }
  }

  #pragma unroll
  for (int n = 0; n < 2; n++){
    int gc = c0 + wn * 32 + n * 16 + l16;
    float bv = bias[gc];
    #pragma unroll
    for (int m = 0; m < 2; m++){
      int grb = r0 + wm * 32 + m * 16 + grp * 4;
      #pragma unroll
      for (int r = 0; r < 4; r++)
        C[(size_t)(grb + r) * N + gc] = (unsigned short)bf16_rne(acc[m][n][r] + bv);
    }
  }
}

// ------- self-attention: bf16 MFMA flash, KEY-SPLIT x4, FIXED-SHIFT softmax ---------
#define KSTR 40
#define VSTR 70
#define PSTR 72
__global__ __launch_bounds__(256)
void sa_attn_mfma(const unsigned short* __restrict__ qkv,
                  unsigned short* __restrict__ opart, float* __restrict__ lb){
  int mz = blockIdx.z;
  int m = mz & 3, split = mz >> 2;           // split 0..3
  int h = blockIdx.y;
  int tid  = threadIdx.x;
  int wave = tid >> 6, lane = tid & 63;
  int qr = lane & 15, grp = lane >> 4;
  int q0 = blockIdx.x * 64 + wave * 16;

  int kt0 = split ? (7 + (split - 1) * 6) : 0;
  int kt1 = kt0 + (split ? 6 : 7);

  __shared__ unsigned short Kls[2][64 * KSTR];
  __shared__ unsigned short Vls[2][32 * VSTR];
  __shared__ unsigned short Pls[4][16 * PSTR];
  unsigned short* Pw = Pls[wave];

  short8 qf = *(const short8*)(qkv + ((size_t)(m * NCTX + q0 + qr)) * 768 + h * 32 + grp * 8);

  int skey = tid >> 2;
  int scol = (tid & 3) * 8;
  const unsigned short* kbase = qkv + (size_t)m * NCTX * 768 + 256 + h * 32 + scol;

  uint4 kreg = *(const uint4*)(kbase + (size_t)(kt0 * 64 + skey) * 768);
  uint4 vreg = *(const uint4*)(kbase + (size_t)(kt0 * 64 + skey) * 768 + 256);

  float lq = 0.0f;                       // per-thread partial sum of P
  f32x4 acc0 = {0.f, 0.f, 0.f, 0.f};
  f32x4 acc1 = {0.f, 0.f, 0.f, 0.f};

  {
    *(uint4*)&Kls[0][skey * KSTR + scol] = kreg;
    unsigned int vv[4] = {vreg.x, vreg.y, vreg.z, vreg.w};
    #pragma unroll
    for (int j = 0; j < 4; j++){
      Vls[0][(scol + 2 * j    ) * VSTR + skey] = (unsigned short)(vv[j] & 0xffffu);
      Vls[0][(scol + 2 * j + 1) * VSTR + skey] = (unsigned short)(vv[j] >> 16);
    }
  }

  for (int kt = kt0; kt < kt1; kt++){
    int b = (kt - kt0) & 1;
    __syncthreads();
    if (kt + 1 < kt1){
      kreg = *(const uint4*)(kbase + (size_t)((kt + 1) * 64 + skey) * 768);
      vreg = *(const uint4*)(kbase + (size_t)((kt + 1) * 64 + skey) * 768 + 256);
    }

    f32x4 s0 = {0.f,0.f,0.f,0.f}, s1 = {0.f,0.f,0.f,0.f};
    f32x4 s2 = {0.f,0.f,0.f,0.f}, s3 = {0.f,0.f,0.f,0.f};
    {
      const short8 k0 = *(const short8*)&Kls[b][( 0 + qr) * KSTR + grp * 8];
      const short8 k1 = *(const short8*)&Kls[b][(16 + qr) * KSTR + grp * 8];
      const short8 k2 = *(const short8*)&Kls[b][(32 + qr) * KSTR + grp * 8];
      const short8 k3 = *(const short8*)&Kls[b][(48 + qr) * KSTR + grp * 8];
      s0 = __builtin_amdgcn_mfma_f32_16x16x32_bf16(k0, qf, s0, 0, 0, 0);
      s1 = __builtin_amdgcn_mfma_f32_16x16x32_bf16(k1, qf, s1, 0, 0, 0);
      s2 = __builtin_amdgcn_mfma_f32_16x16x32_bf16(k2, qf, s2, 0, 0, 0);
      s3 = __builtin_amdgcn_mfma_f32_16x16x32_bf16(k3, qf, s3, 0, 0, 0);
    }

    float p[4][4];
    #pragma unroll
    for (int r = 0; r < 4; r++){
      p[0][r] = EXP2(s0[r]); p[1][r] = EXP2(s1[r]);
      p[2][r] = EXP2(s2[r]); p[3][r] = EXP2(s3[r]);
    }
    #pragma unroll
    for (int kb = 0; kb < 4; kb++)
      #pragma unroll
      for (int r = 0; r < 4; r++) lq += p[kb][r];

    #pragma unroll
    for (int kb = 0; kb < 4; kb++){
      *(unsigned int*)&Pw[qr * PSTR + kb * 16 + grp * 4]     = pack_bf16x2(p[kb][0], p[kb][1]);
      *(unsigned int*)&Pw[qr * PSTR + kb * 16 + grp * 4 + 2] = pack_bf16x2(p[kb][2], p[kb][3]);
    }

    #pragma unroll
    for (int hh = 0; hh < 2; hh++){
      const short8 pf = *(const short8*)&Pw[qr * PSTR + hh * 32 + grp * 8];
      const short8 v0 = *(const short8*)&Vls[b][( 0 + qr) * VSTR + hh * 32 + grp * 8];
      const short8 v1 = *(const short8*)&Vls[b][(16 + qr) * VSTR + hh * 32 + grp * 8];
      acc0 = __builtin_amdgcn_mfma_f32_16x16x32_bf16(v0, pf, acc0, 0, 0, 0);
      acc1 = __builtin_amdgcn_mfma_f32_16x16x32_bf16(v1, pf, acc1, 0, 0, 0);
    }

    if (kt + 1 < kt1){
      *(uint4*)&Kls[b ^ 1][skey * KSTR + scol] = kreg;
      unsigned int vv[4] = {vreg.x, vreg.y, vreg.z, vreg.w};
      #pragma unroll
      for (int j = 0; j < 4; j++){
        Vls[b ^ 1][(scol + 2 * j    ) * VSTR + skey] = (unsigned short)(vv[j] & 0xffffu);
        Vls[b ^ 1][(scol + 2 * j + 1) * VSTR + skey] = (unsigned short)(vv[j] >> 16);
      }
    }
  }

  lq += __shfl_xor(lq, 16);
  lq += __shfl_xor(lq, 32);
  float inv = 1.0f / lq;
  int gr = m * NCTX + q0 + qr;
  unsigned short* op = opart + ((size_t)(split * RC + gr)) * DMODEL + h * DHEAD;
  uint2 o16a, o16b;
  o16a.x = pack_bf16x2(acc0[0] * inv, acc0[1] * inv);
  o16a.y = pack_bf16x2(acc0[2] * inv, acc0[3] * inv);
  o16b.x = pack_bf16x2(acc1[0] * inv, acc1[1] * inv);
  o16b.y = pack_bf16x2(acc1[2] * inv, acc1[3] * inv);
  *(uint2*)(op + grp * 4)      = o16a;
  *(uint2*)(op + 16 + grp * 4) = o16b;
  if (grp == 0)
    lb[((size_t)(split * RC + gr)) * 8 + h] = lq;
}

// ------- key-split merge (4-way): out = sum_i l_i*O_i / sum_i l_i -------------------
__global__ __launch_bounds__(256)
void sa_merge(const unsigned short* __restrict__ opart, const float* __restrict__ lb,
              unsigned short* __restrict__ out){
  int g = blockIdx.x * 256 + threadIdx.x;   // over RC*64 (4 dims each)
  int gr = g >> 6;
  int d4 = (g & 63) * 4;
  int h  = d4 >> 5;
  float l[NSPLIT];
  float lsum = 0.f;
  #pragma unroll
  for (int s = 0; s < NSPLIT; s++){
    l[s] = lb[(size_t)(s * RC + gr) * 8 + h];
    lsum += l[s];
  }
  float inv = 1.0f / lsum;
  float o0 = 0.f, o1 = 0.f, o2 = 0.f, o3 = 0.f;
  #pragma unroll
  for (int s = 0; s < NSPLIT; s++){
    float w = l[s] * inv;
    uint2 a = *(const uint2*)(opart + (size_t)(s * RC + gr) * DMODEL + d4);
    o0 += bfu(a.x & 0xffffu) * w;
    o1 += bfu(a.x >> 16)     * w;
    o2 += bfu(a.y & 0xffffu) * w;
    o3 += bfu(a.y >> 16)     * w;
  }
  uint2 w;
  w.x = pack_bf16x2(o0, o1);
  w.y = pack_bf16x2(o2, o3);
  *(uint2*)(out + (size_t)gr * DMODEL + d4) = w;
}

// ------- cross-attention over 9 gathered neighbours (bf16 q/kv, q pre-scaled) -------
__global__ __launch_bounds__(256)
void ca_attn_kernel(const unsigned short* __restrict__ qb, const unsigned short* __restrict__ kv,
                    const int* __restrict__ idx, const float* __restrict__ mask,
                    unsigned short* __restrict__ ob){
  int g = blockIdx.x;
  int m = g >> 11;
  int tid = threadIdx.x;
  float q = bfu(qb[(size_t)g * DMODEL + tid]);
  float s[KNB];
  int rws[KNB];
  #pragma unroll
  for (int k = 0; k < KNB; k++){
    int row = idx[(size_t)g * KNB + k];
    rws[k] = row;
    float p = q * bfu(kv[((size_t)(m * NCTX + row)) * 512 + tid]);
    #pragma unroll
    for (int off = 16; off > 0; off >>= 1) p += __shfl_xor(p, off, 32);
    s[k] = (mask[(size_t)g * KNB + k] > 0.5f) ? p : -1e30f;
  }
  float sm = s[0];
  #pragma unroll
  for (int k = 1; k < KNB; k++) sm = fmaxf(sm, s[k]);
  float den = 0.f, w[KNB];
  #pragma unroll
  for (int k = 0; k < KNB; k++){ w[k] = __expf(s[k] - sm); den += w[k]; }
  float inv = 1.0f / den;
  float o = 0.f;
  #pragma unroll
  for (int k = 0; k < KNB; k++)
    o += w[k] * bfu(kv[((size_t)(m * NCTX + rws[k])) * 512 + 256 + tid]);
  ob[(size_t)g * DMODEL + tid] = (unsigned short)bf16_rne(o * inv);
}

// ---------------- host launch helper ----------------
static inline void launch_gemm(const unsigned short* A, const unsigned short* Wt,
                               const float* bias, const float* res, void* C,
                               int R, int K, int N, int flags, hipStream_t stream){
  if (N == 768){
    gemm_glds<256, 64, 128><<<dim3(N / 128, R / 64), 256, 0, stream>>>(A, Wt, bias, res, C, N, flags);
  } else if (K == 256){
    gemm_glds<256, 64, 64><<<dim3(N / 64, R / 64), 256, 0, stream>>>(A, Wt, bias, res, C, N, flags);
  } else {
    gemm_glds<512, 64, 64><<<dim3(N / 64, R / 64), 256, 0, stream>>>(A, Wt, bias, res, C, N, flags);
  }
}

// ---------------- host launcher ----------------
extern "C" void kernel_launch(void* const* d_in, const int* in_sizes, int n_in,
                              void* d_out, int out_size, void* d_ws, size_t ws_size,
                              hipStream_t stream){
  const float* xc      = (const float*)d_in[0];
  const float* zc_in   = (const float*)d_in[1];
  const float* xt      = (const float*)d_in[2];
  const float* zt_in   = (const float*)d_in[3];
  const float* sa_wqkv = (const float*)d_in[4];
  const float* sa_wo   = (const float*)d_in[5];
  const float* sa_ln1  = (const float*)d_in[6];
  const float* sa_ln2  = (const float*)d_in[7];
  const float* sa_w1   = (const float*)d_in[8];
  const float* sa_b1   = (const float*)d_in[9];
  const float* sa_w2   = (const float*)d_in[10];
  const float* sa_b2   = (const float*)d_in[11];
  const float* ca_wq   = (const float*)d_in[12];
  const float* ca_wkv  = (const float*)d_in[13];
  const float* ca_wo   = (const float*)d_in[14];
  const float* ca_lnq  = (const float*)d_in[15];
  const float* ca_lnkv = (const float*)d_in[16];
  const float* ca_ln2  = (const float*)d_in[17];
  const float* ca_w1   = (const float*)d_in[18];
  const float* ca_b1   = (const float*)d_in[19];
  const float* ca_w2   = (const float*)d_in[20];
  const float* ca_b2   = (const float*)d_in[21];

  if (ws_size < (size_t)WS_FLOATS * sizeof(float)) return;
  float* ws    = (float*)d_ws;
  float* zc    = ws + ZC_OFF;
  unsigned short* hc16 = (unsigned short*)(ws + HC_OFF);   // normalize(zc) bf16
  unsigned short* ht16 = (unsigned short*)(ws + HT_OFF);   // normalize(zt) / SA merged out
  float* qkvb  = ws + QKV_OFF;   // aliased: bf16 qkv / bf16 CA kv / bf16 ffn-mid
  unsigned short* qkv16 = (unsigned short*)qkvb;
  unsigned short* wt    = (unsigned short*)(ws + WT_OFF);
  float* fb    = ws + FB_OFF;
  unsigned short* qb16 = (unsigned short*)(ws + Q_OFF);    // CA q bf16
  unsigned short* ob16    = (unsigned short*)(ws + O_OFF); // CA out
  unsigned short* opart16 = (unsigned short*)(ws + OPART_OFF);
  float* lbuf  = ws + LB_OFF;
  int*   idxb  = (int*)(ws + IDX_OFF);
  float* maskb = ws + MASK_OFF;
  float* zt    = (float*)d_out;

  const float QSC = ATTN_SCALE * L2E;   // folded into sa Q (exp2-domain softmax)

  // ---- weight prep (transpose + gamma row-scale + Q col-scale) ----
  TTable tt;
  for (int l = 0; l < LAYERS; l++){
    int b = l * WT_LAYER, i = l * 9;
    tt.e[i + 0] = { sa_wqkv + (size_t)l * 256 * 768, sa_ln1  + l * 512, b + WT_QKV,  256, 768, 256, QSC };
    tt.e[i + 1] = { sa_wo   + (size_t)l * 256 * 256, nullptr,           b + WT_WO,   256, 256, 0, 1.f };
    tt.e[i + 2] = { sa_w1   + (size_t)l * 256 * 512, sa_ln2  + l * 512, b + WT_W1,   256, 512, 0, 1.f };
    tt.e[i + 3] = { sa_w2   + (size_t)l * 512 * 256, nullptr,           b + WT_W2,   512, 256, 0, 1.f };
    tt.e[i + 4] = { ca_wq   + (size_t)l * 256 * 256, ca_lnq  + l * 512, b + WT_CWQ,  256, 256, 256, ATTN_SCALE };
    tt.e[i + 5] = { ca_wkv  + (size_t)l * 256 * 512, ca_lnkv + l * 512, b + WT_CWKV, 256, 512, 0, 1.f };
    tt.e[i + 6] = { ca_wo   + (size_t)l * 256 * 256, nullptr,           b + WT_CWO,  256, 256, 0, 1.f };
    tt.e[i + 7] = { ca_w1   + (size_t)l * 256 * 512, ca_ln2  + l * 512, b + WT_CW1,  256, 512, 0, 1.f };
    tt.e[i + 8] = { ca_w2   + (size_t)l * 512 * 256, nullptr,           b + WT_CW2,  512, 256, 0, 1.f };
  }
  wprep_kernel<<<dim3(24, 16, 18), dim3(32, 8), 0, stream>>>(tt, wt);

  // ---- beta fold into biases (parallel; Q-part scaled to match) ----
  BTable bt;
  for (int l = 0; l < LAYERS; l++){
    int fo = l * FB_LAYER, i = l * 5;
    bt.e[i + 0] = { sa_wqkv + (size_t)l * 256 * 768, sa_ln1  + l * 512 + 256, nullptr,        fo + FB_QKV, 768, 256, QSC };
    bt.e[i + 1] = { sa_w1   + (size_t)l * 256 * 512, sa_ln2  + l * 512 + 256, sa_b1 + l * FF, fo + FB_W1,  512, 0, 1.f };
    bt.e[i + 2] = { ca_wkv  + (size_t)l * 256 * 512, ca_lnkv + l * 512 + 256, nullptr,        fo + FB_WKV, 512, 0, 1.f };
    bt.e[i + 3] = { ca_wq   + (size_t)l * 256 * 256, ca_lnq  + l * 512 + 256, nullptr,        fo + FB_WQ,  256, 256, ATTN_SCALE };
    bt.e[i + 4] = { ca_w1   + (size_t)l * 256 * 512, ca_ln2  + l * 512 + 256, ca_b1 + l * FF, fo + FB_CW1, 512, 0, 1.f };
  }
  bfold_kernel<<<dim3(10, 12), 256, 0, stream>>>(bt, fb);

  nn_idx_kernel<<<(MB * NTGT) / 256, 256, 0, stream>>>(xc, xt, idxb, maskb);

  // upfront normalize(zc); post-FFN normalize is shared by ca_wkv and next-layer qkv
  ln_norm<<<RC / 4, 256, 0, stream>>>(zc_in, hc16, RC);

  for (int l = 0; l < LAYERS; l++){
    const unsigned short* wl = wt + (size_t)l * WT_LAYER;
    const float* fl = fb + (size_t)l * FB_LAYER;
    const float* zc_src = (l == 0) ? zc_in : zc;
    const float* zt_src = (l == 0) ? zt_in : zt;

    // ---------- self-attention block on zc ----------
    launch_gemm(hc16, wl + WT_QKV, fl + FB_QKV, nullptr, qkv16, RC, 256, 768, 1 | 8, stream);
    sa_attn_mfma<<<dim3(NCTX / 64, NHEAD, MB * NSPLIT), 256, 0, stream>>>(qkv16, opart16, lbuf);
    sa_merge<<<RC * 64 / 256, 256, 0, stream>>>(opart16, lbuf, ht16);
    launch_gemm(ht16, wl + WT_WO, nullptr, zc_src, zc, RC, 256, 256, 4, stream);
    ln_norm<<<RC / 4, 256, 0, stream>>>(zc, hc16, RC);
    launch_gemm(hc16, wl + WT_W1, fl + FB_W1, nullptr, qkv16, RC, 256, 512, 1 | 2 | 8, stream);
    launch_gemm(qkv16, wl + WT_W2, sa_b2 + l * DMODEL, zc, zc, RC, 512, 256, 1 | 4, stream);

    // ---------- cross-attention block on zt ----------
    // one dispatch normalizes zc (post-FFN; shared by ca_wkv + next-layer qkv) AND zt_src
    ln_norm2<<<(RC + RT) / 4, 256, 0, stream>>>(zc, hc16, RC, zt_src, ht16);
    gemm_wkvq<<<dim3(8, RT / 64, 2), 256, 0, stream>>>(
        hc16, wl + WT_CWKV, fl + FB_WKV, qkv16,
        ht16, wl + WT_CWQ,  fl + FB_WQ,  qb16);
    ca_attn_kernel<<<RT, 256, 0, stream>>>(qb16, qkv16, idxb, maskb, ob16);
    launch_gemm(ob16, wl + WT_CWO, nullptr, zt_src, zt, RT, 256, 256, 4, stream);
    ln_norm<<<RT / 4, 256, 0, stream>>>(zt, ht16, RT);
    launch_gemm(ht16, wl + WT_CW1, fl + FB_CW1, nullptr, qkv16, RT, 256, 512, 1 | 2 | 8, stream);
    launch_gemm(qkv16, wl + WT_CW2, ca_b2 + l * DMODEL, zt, zt, RT, 512, 256, 1 | 4, stream);
  }
}